// Round 1
// baseline (793.960 us; speedup 1.0000x reference)
//
#include <hip/hip_runtime.h>
#include <hip/hip_bf16.h>

#define NDIM 2048
#define BS   64
#define NM4  (NDIM * NDIM / 4)
#define BSN  ((size_t)BS * NDIM)
#define SMEM_BYTES 69632   // wgemm: 4x16KB pipeline (+ 34.8KB transpose reuse); skinny: 64KB+4KB

typedef __bf16 bf16_t;
typedef __bf16 bf16x4 __attribute__((ext_vector_type(4)));
typedef __bf16 bf16x8 __attribute__((ext_vector_type(8)));
typedef float  f32x4  __attribute__((ext_vector_type(4)));

// Async global->LDS, 16 B per lane.  LDS dest = wave-uniform base + lane*16.
__device__ __forceinline__ void gload16(const void* g, void* lds) {
  __builtin_amdgcn_global_load_lds(
      (const __attribute__((address_space(1))) void*)g,
      (__attribute__((address_space(3))) void*)lds, 16, 0, 0);
}
// 32-bit LDS byte offset of a generic pointer into __shared__.
__device__ __forceinline__ uint32_t lds_off(void* p) {
  return (uint32_t)(uintptr_t)(__attribute__((address_space(3))) void*)p;
}

#define WB4 asm volatile("s_waitcnt vmcnt(4)\n\ts_barrier" ::: "memory")
#define WB2 asm volatile("s_waitcnt vmcnt(2)\n\ts_barrier" ::: "memory")
#define WB0 asm volatile("s_waitcnt vmcnt(0)\n\ts_barrier" ::: "memory")

// ---------------------------------------------------------------------------
// prep (512 thr, 3072 blocks): b<1024 convert H,U (+y, traj0); else 64x64
// fp32->bf16 vectorized transposes of Dinv, invM.
// ---------------------------------------------------------------------------
__global__ __launch_bounds__(512) void prep(
    const float* __restrict__ H, const float* __restrict__ U,
    const float* __restrict__ Dinv, const float* __restrict__ invM,
    const float* __restrict__ y,
    bf16_t* __restrict__ H16, bf16_t* __restrict__ U16,
    bf16_t* __restrict__ Dt, bf16_t* __restrict__ iMt,
    bf16_t* __restrict__ y16, float* __restrict__ traj0) {
  __shared__ bf16_t tile[64][72];
  int b = blockIdx.x, tid = threadIdx.x;
  if (b < 1024) {
#pragma unroll
    for (int i = 0; i < 4; ++i) {
      int idx = b * 2048 + i * 512 + tid;
      const float* src = (idx < NM4) ? H : U;
      bf16_t* dst = (idx < NM4) ? H16 : U16;
      int j = (idx < NM4) ? idx : idx - NM4;
      float4 v = ((const float4*)src)[j];
      bf16x4 o = {(bf16_t)v.x, (bf16_t)v.y, (bf16_t)v.z, (bf16_t)v.w};
      ((bf16x4*)dst)[j] = o;
    }
    int yi = b * 512 + tid;
    if (yi < BS * NDIM / 4) {
      float4 w = ((const float4*)y)[yi];
      bf16x4 o2 = {(bf16_t)w.x, (bf16_t)w.y, (bf16_t)w.z, (bf16_t)w.w};
      ((bf16x4*)y16)[yi] = o2;
      ((float4*)traj0)[yi] = make_float4(0.f, 0.f, 0.f, 0.f);
    }
  } else {
    int id = b - 1024;
    const float* src = (id < 1024) ? Dinv : invM;
    bf16_t* dst = (id < 1024) ? Dt : iMt;
    id &= 1023;
    int bx = id & 31, by = id >> 5;
    int r = tid >> 3, c8 = (tid & 7) * 8;
    const float* sp = src + (size_t)(by * 64 + r) * NDIM + bx * 64 + c8;
    float4 v0 = *(const float4*)sp;
    float4 v1 = *(const float4*)(sp + 4);
    bf16_t* t = &tile[r][c8];
    t[0] = (bf16_t)v0.x; t[1] = (bf16_t)v0.y; t[2] = (bf16_t)v0.z; t[3] = (bf16_t)v0.w;
    t[4] = (bf16_t)v1.x; t[5] = (bf16_t)v1.y; t[6] = (bf16_t)v1.z; t[7] = (bf16_t)v1.w;
    __syncthreads();
    bf16x8 o;
#pragma unroll
    for (int j = 0; j < 8; ++j) o[j] = tile[c8 + j][r];
    *(bf16x8*)(dst + (size_t)(bx * 64 + r) * NDIM + by * 64 + c8) = o;
  }
}

// ---------------------------------------------------------------------------
// wgemm v5: 2048^3 NT GEMM, 512 thr, 128x128 tile, BK=32, 64 chunks, 4-stage
// async pipeline.  Fragment loads are raw asm ds_read_b128 (invisible to
// the compiler's waitcnt pass, so it cannot insert vmcnt(0) drains); data
// readiness enforced by an lgkmcnt(0) asm that redefines the fragment regs.
// NEW: XCD-region tile swizzle.  blockIdx%8 selects the XCD; each XCD owns a
// compact 4x8 region of the 16x16 tile grid, cutting the per-chunk unique L2
// footprint from 144KB (16 A-panels + 2 B-panels) to 96KB (4 A + 8 B).
// Optional transposed store Ct via LDS round-trip in the freed buffers.
// ---------------------------------------------------------------------------
__device__ __forceinline__ void wgemm_role(
    const bf16_t* __restrict__ A, const bf16_t* __restrict__ Bt,
    bf16_t* __restrict__ C, bf16_t* __restrict__ Ct, int blk, char* smem) {
  int tid = threadIdx.x, lane = tid & 63, wave = tid >> 6;
  // XCD-region swizzle: xcd = blk&7 (dispatch round-robin), 32 blocks/XCD
  // form a 4(row) x 8(col) tile region.  Bijective over [0,256).
  int xcd = blk & 7, jj = blk >> 3;
  int m0 = (((xcd >> 1) << 2) + (jj >> 3)) * 128;
  int n0 = (((xcd & 1) << 3) + (jj & 7)) * 128;
  int rl = lane & 15, q = lane >> 4;
  const bf16_t* Ag = A  + (size_t)(m0 + wave * 16 + rl) * NDIM + q * 8;
  const bf16_t* Bg = Bt + (size_t)(n0 + wave * 16 + rl) * NDIM + q * 8;
  char* ldsA = smem + wave * 1024;          // staging slice (this wave) + stage*16384
  char* ldsB = smem + 8192 + wave * 1024;

  int wr2 = (wave & 3) * 2, wc4 = (wave >> 2) * 4;
  uint32_t abase = lds_off(smem) + wr2 * 1024 + lane * 16;
  uint32_t bbase = lds_off(smem) + 8192 + wc4 * 1024 + lane * 16;

  f32x4 acc[2][4];
#pragma unroll
  for (int i = 0; i < 2; ++i)
#pragma unroll
    for (int j = 0; j < 4; ++j) acc[i][j] = (f32x4){0.f, 0.f, 0.f, 0.f};

#define STAGE(s)                                  \
  {                                               \
    int _b = (s) & 3, _k = (s) * 32;              \
    gload16(Ag + _k, ldsA + _b * 16384);          \
    gload16(Bg + _k, ldsB + _b * 16384);          \
  }
#define COMPUTE(bb)                                                            \
  {                                                                            \
    uint32_t av = abase + (bb) * 16384;                                        \
    uint32_t bv = bbase + (bb) * 16384;                                        \
    bf16x8 af0, af1, bg0, bg1, bg2, bg3;                                       \
    asm volatile("ds_read_b128 %0, %1"             : "=v"(af0) : "v"(av));     \
    asm volatile("ds_read_b128 %0, %1 offset:1024" : "=v"(af1) : "v"(av));     \
    asm volatile("ds_read_b128 %0, %1"             : "=v"(bg0) : "v"(bv));     \
    asm volatile("ds_read_b128 %0, %1 offset:1024" : "=v"(bg1) : "v"(bv));     \
    asm volatile("ds_read_b128 %0, %1 offset:2048" : "=v"(bg2) : "v"(bv));     \
    asm volatile("ds_read_b128 %0, %1 offset:3072" : "=v"(bg3) : "v"(bv));     \
    asm volatile("s_waitcnt lgkmcnt(0)"                                        \
                 : "+v"(af0), "+v"(af1), "+v"(bg0), "+v"(bg1), "+v"(bg2),      \
                   "+v"(bg3));                                                 \
    acc[0][0] = __builtin_amdgcn_mfma_f32_16x16x32_bf16(af0, bg0, acc[0][0], 0, 0, 0); \
    acc[0][1] = __builtin_amdgcn_mfma_f32_16x16x32_bf16(af0, bg1, acc[0][1], 0, 0, 0); \
    acc[0][2] = __builtin_amdgcn_mfma_f32_16x16x32_bf16(af0, bg2, acc[0][2], 0, 0, 0); \
    acc[0][3] = __builtin_amdgcn_mfma_f32_16x16x32_bf16(af0, bg3, acc[0][3], 0, 0, 0); \
    acc[1][0] = __builtin_amdgcn_mfma_f32_16x16x32_bf16(af1, bg0, acc[1][0], 0, 0, 0); \
    acc[1][1] = __builtin_amdgcn_mfma_f32_16x16x32_bf16(af1, bg1, acc[1][1], 0, 0, 0); \
    acc[1][2] = __builtin_amdgcn_mfma_f32_16x16x32_bf16(af1, bg2, acc[1][2], 0, 0, 0); \
    acc[1][3] = __builtin_amdgcn_mfma_f32_16x16x32_bf16(af1, bg3, acc[1][3], 0, 0, 0); \
  }

  STAGE(0); STAGE(1); STAGE(2);
  int s = 3;
#pragma unroll 1
  for (int k = 0; k < 60; k += 4) {
    WB4; STAGE(s); ++s; COMPUTE(0);
    WB4; STAGE(s); ++s; COMPUTE(1);
    WB4; STAGE(s); ++s; COMPUTE(2);
    WB4; STAGE(s); ++s; COMPUTE(3);
  }
  WB4; STAGE(63); COMPUTE(0);   // chunk 60
  WB4; COMPUTE(1);              // chunk 61
  WB2; COMPUTE(2);              // chunk 62
  WB0; COMPUTE(3);              // chunk 63
#undef STAGE
#undef COMPUTE

  // normal-orientation store (C[m][n])
#pragma unroll
  for (int i = 0; i < 2; ++i)
#pragma unroll
    for (int j = 0; j < 4; ++j)
#pragma unroll
      for (int r = 0; r < 4; ++r)
        C[(size_t)(m0 + (wr2 + i) * 16 + q * 4 + r) * NDIM + n0 + (wc4 + j) * 16 + rl] =
            (bf16_t)acc[i][j][r];

  // optional transposed store (Ct[n][m]) via LDS round-trip
  if (Ct) {
    __syncthreads();
    bf16_t (*tileT)[136] = (bf16_t(*)[136])smem;   // 128 x 136 x 2 B = 34.8 KB
#pragma unroll
    for (int i = 0; i < 2; ++i)
#pragma unroll
      for (int j = 0; j < 4; ++j)
#pragma unroll
        for (int r = 0; r < 4; ++r)
          tileT[(wc4 + j) * 16 + rl][(wr2 + i) * 16 + q * 4 + r] = (bf16_t)acc[i][j][r];
    __syncthreads();
#pragma unroll
    for (int t = 0; t < 4; ++t) {
      int v = t * 512 + tid, row = v >> 4, c8 = (v & 15) * 8;
      *(bf16x8*)(Ct + (size_t)(n0 + row) * NDIM + m0 + c8) = *(bf16x8*)&tileT[row][c8];
    }
  }
}

// ---------------------------------------------------------------------------
// skinny v3: C[64,16] = add + sign*(A[64,2048] @ Bt^T cols n0..+15).
// Panel (64 KB, fragment order) staged async; waves 0-3 K-half0 / 4-7 K-half1;
// 8 round-robin accumulators; LDS f32 reduction joins halves.
// ---------------------------------------------------------------------------
__device__ __forceinline__ void skinny_role(
    const bf16_t* __restrict__ A, const bf16_t* __restrict__ Bt, int n0, char* smem,
    const float* __restrict__ add, float sign,
    float* o32, float* o32b, bf16_t* o16) {
  int tid = threadIdx.x, lane = tid & 63, wave = tid >> 6;
  int rl = lane & 15, q = lane >> 4;
#pragma unroll
  for (int i = 0; i < 8; ++i) {
    const bf16_t* g = Bt + (size_t)(n0 + rl) * NDIM + (i * 8 + wave) * 32 + q * 8;
    gload16(g, smem + (size_t)(i * 512 + wave * 64) * 16);
  }
  __syncthreads();

  int ms = (wave & 3) * 16, kh = wave >> 2;
  const bf16x8* Ap = (const bf16x8*)(A + (size_t)(ms + rl) * NDIM) + q + kh * 128;
  const bf16x8* Bp = (const bf16x8*)smem + lane + kh * 2048;

  f32x4 acc[8];
#pragma unroll
  for (int i = 0; i < 8; ++i) acc[i] = (f32x4){0.f, 0.f, 0.f, 0.f};
#pragma unroll
  for (int c = 0; c < 32; ++c)
    acc[c & 7] = __builtin_amdgcn_mfma_f32_16x16x32_bf16(Ap[c * 4], Bp[c * 64], acc[c & 7], 0, 0, 0);
  f32x4 s = ((acc[0] + acc[1]) + (acc[2] + acc[3])) + ((acc[4] + acc[5]) + (acc[6] + acc[7]));

  f32x4* red = (f32x4*)(smem + 65536);
  if (wave >= 4) red[(wave & 3) * 64 + lane] = s;
  __syncthreads();
  if (wave < 4) {
    s += red[wave * 64 + lane];
    int mrow = ms + q * 4, col = n0 + rl;
#pragma unroll
    for (int r = 0; r < 4; ++r) {
      size_t o = (size_t)(mrow + r) * NDIM + col;
      float v = sign * s[r];
      if (add) v += add[o];
      if (o32)  o32[o]  = v;
      if (o32b) o32b[o] = v;
      if (o16)  o16[o]  = (bf16_t)v;
    }
  }
}

// --------------------------- mega nodes (512 thr) --------------------------
// A: W = U@invM, dual store Wrm+Wt (256 wgemm) || yMF = y@H^T (128 skinny)
__global__ __launch_bounds__(512, 4) void megaA(
    const bf16_t* __restrict__ U16, const bf16_t* __restrict__ iMt16,
    const bf16_t* __restrict__ y16, const bf16_t* __restrict__ H16,
    bf16_t* __restrict__ Wrm, bf16_t* __restrict__ Wt, bf16_t* __restrict__ yMF16) {
  __shared__ char smem[SMEM_BYTES];
  int b = blockIdx.x;
  if (b < 256) wgemm_role(U16, iMt16, Wrm, Wt, b, smem);
  else         skinny_role(y16, H16, (b - 256) * 16, smem, nullptr, 1.f, nullptr, nullptr, yMF16);
}

// B (light): c = yMF@invM (128) || x0 = yMF@Dinv (128 -> z0)
__global__ __launch_bounds__(512, 4) void megaB(
    const bf16_t* __restrict__ yMF16, const bf16_t* __restrict__ iMt16,
    const bf16_t* __restrict__ Dt16,
    float* __restrict__ c32, bf16_t* __restrict__ c16, bf16_t* __restrict__ z0) {
  __shared__ char smem[SMEM_BYTES];
  int b = blockIdx.x;
  if (b < 128) skinny_role(yMF16, iMt16, b * 16, smem, nullptr, 1.f, c32, nullptr, c16);
  else         skinny_role(yMF16, Dt16, (b - 128) * 16, smem, nullptr, 1.f, nullptr, nullptr, z0);
}

// C: W2 = NT(Wt,Wrm), dual store W2t+W2rm (256) || x1 (128 -> traj[1], z0+BSN)
//    || c2 (128)
__global__ __launch_bounds__(512, 4) void megaC(
    const bf16_t* __restrict__ Wt, const bf16_t* __restrict__ Wrm,
    const bf16_t* __restrict__ z0, const bf16_t* __restrict__ c16,
    const float* __restrict__ c32,
    bf16_t* __restrict__ W2t, bf16_t* __restrict__ W2rm,
    float* __restrict__ traj1, bf16_t* __restrict__ z0b,
    float* __restrict__ c2_32, bf16_t* __restrict__ c2_16) {
  __shared__ char smem[SMEM_BYTES];
  int b = blockIdx.x;
  if (b < 256)      wgemm_role(Wt, Wrm, W2t, W2rm, b, smem);
  else if (b < 384) skinny_role(z0, Wt, (b - 256) * 16, smem, c32, -1.f, traj1, nullptr, z0b);
  else              skinny_role(c16, Wt, (b - 384) * 16, smem, c32, -1.f, c2_32, nullptr, c2_16);
}

// D (light): x2 (128 -> traj[2], zA0) || x3 (128 -> traj[3], zA1) || c4 (128)
__global__ __launch_bounds__(512, 4) void megaD(
    const bf16_t* __restrict__ W2t, const bf16_t* __restrict__ z0,
    const bf16_t* __restrict__ c2_16, const float* __restrict__ c2_32,
    float* __restrict__ traj2, float* __restrict__ traj3,
    bf16_t* __restrict__ zA, float* __restrict__ c4_32) {
  __shared__ char smem[SMEM_BYTES];
  int b = blockIdx.x;
  if (b < 128)      skinny_role(z0, W2t, b * 16, smem, c2_32, 1.f, traj2, nullptr, zA);
  else if (b < 256) skinny_role(z0 + BSN, W2t, (b - 128) * 16, smem, c2_32, 1.f, traj3, nullptr, zA + BSN);
  else              skinny_role(c2_16, W2t, (b - 256) * 16, smem, c2_32, 1.f, c4_32, nullptr, nullptr);
}

// E: W4t = NT(W2t,W2rm) (256) || x4 (128 -> traj[4], zA2) || x5 (128 -> traj[5], zA3)
__global__ __launch_bounds__(512, 4) void megaE(
    const bf16_t* __restrict__ W2t, const bf16_t* __restrict__ W2rm,
    const bf16_t* __restrict__ zA_in, const float* __restrict__ c2_32,
    bf16_t* __restrict__ W4t, float* __restrict__ traj4, float* __restrict__ traj5,
    bf16_t* __restrict__ zA) {
  __shared__ char smem[SMEM_BYTES];
  int b = blockIdx.x;
  if (b < 256)      wgemm_role(W2t, W2rm, W4t, nullptr, b, smem);
  else if (b < 384) skinny_role(zA_in, W2t, (b - 256) * 16, smem, c2_32, 1.f, traj4, nullptr, zA + 2 * BSN);
  else              skinny_role(zA_in + BSN, W2t, (b - 384) * 16, smem, c2_32, 1.f, traj5, nullptr, zA + 3 * BSN);
}

// ---------------------------------------------------------------------------
// quad_fused: all 5 quad steps (x_{k+4} = c4 + x_k@W4, 4 chains) in ONE
// launch.  512 blocks (chain ci=b&3, panel p=b>>2) == exact residency
// capacity (69.6 KB LDS -> 2 blocks/CU, 16 waves/CU), so a device-scope
// atomic arrive+spin barrier between steps is deadlock-free.  The 64 KB W4t
// panel is staged into LDS ONCE and reused across all 5 steps (was re-staged
// per launch before).  Release: __syncthreads (drains stores) + tid0
// __threadfence + atomicAdd; acquire: spin on atomicAdd(,0) + __threadfence.
// Note ci = b&3 is a function of b&7 (the XCD), so each XCD touches one
// chain's z only -> z reads stay L2-local per step.
// ---------------------------------------------------------------------------
__global__ __launch_bounds__(512, 4) void quad_fused(
    const bf16_t* __restrict__ z_in, const bf16_t* __restrict__ W4t,
    const float* __restrict__ c4_32, float* __restrict__ traj6,
    bf16_t* __restrict__ zping, bf16_t* __restrict__ zpong,
    float* __restrict__ sfin, int* __restrict__ bar) {
  __shared__ char smem[SMEM_BYTES];
  int b = blockIdx.x, ci = b & 3, p = b >> 2;
  int tid = threadIdx.x, lane = tid & 63, wave = tid >> 6;
  int rl = lane & 15, q = lane >> 4;
  int n0 = p * 16;
  // stage W4t panel once (fragment order), reused for all 5 steps
#pragma unroll
  for (int i = 0; i < 8; ++i) {
    const bf16_t* g = W4t + (size_t)(n0 + rl) * NDIM + (i * 8 + wave) * 32 + q * 8;
    gload16(g, smem + (size_t)(i * 512 + wave * 64) * 16);
  }
  __syncthreads();

  int ms = (wave & 3) * 16, kh = wave >> 2;
  const bf16x8* Bp = (const bf16x8*)smem + lane + kh * 2048;
  f32x4* red = (f32x4*)(smem + 65536);
  const bf16_t* zcur = z_in + (size_t)ci * BSN;

#pragma unroll 1
  for (int g = 0; g < 5; ++g) {
    const bf16x8* Ap = (const bf16x8*)(zcur + (size_t)(ms + rl) * NDIM) + q + kh * 128;
    f32x4 acc[8];
#pragma unroll
    for (int i = 0; i < 8; ++i) acc[i] = (f32x4){0.f, 0.f, 0.f, 0.f};
#pragma unroll
    for (int c = 0; c < 32; ++c)
      acc[c & 7] = __builtin_amdgcn_mfma_f32_16x16x32_bf16(Ap[c * 4], Bp[c * 64], acc[c & 7], 0, 0, 0);
    f32x4 s = ((acc[0] + acc[1]) + (acc[2] + acc[3])) + ((acc[4] + acc[5]) + (acc[6] + acc[7]));

    if (wave >= 4) red[(wave & 3) * 64 + lane] = s;
    __syncthreads();
    bf16_t* zn = ((g & 1) ? zping : zpong) + (size_t)ci * BSN;
    if (wave < 4) {
      s += red[wave * 64 + lane];
      int mrow = ms + q * 4, col = n0 + rl;
      float* tj = traj6 + (size_t)(4 * g + ci) * BSN;
#pragma unroll
      for (int r = 0; r < 4; ++r) {
        size_t o = (size_t)(mrow + r) * NDIM + col;
        float v = c4_32[o] + s[r];
        tj[o] = v;
        zn[o] = (bf16_t)v;
        if (g == 4 && ci == 3) sfin[o] = v;
      }
    }
    zcur = zn;
    if (g < 4) {
      __syncthreads();              // all waves: red reads done, stores drained
      if (tid == 0) {
        __threadfence();            // release: make this block's z stores visible
        atomicAdd(&bar[g], 1);
        while (atomicAdd(&bar[g], 0) < (int)gridDim.x) __builtin_amdgcn_s_sleep(2);
      }
      __syncthreads();
      __threadfence();              // acquire: invalidate stale cached z lines
    }
  }
}

// ---------------------------------------------------------------------------
// Host driver: memset + 7 kernel nodes (was 11 kernels).
// ---------------------------------------------------------------------------
extern "C" void kernel_launch(void* const* d_in, const int* in_sizes, int n_in,
                              void* d_out, int out_size, void* d_ws, size_t ws_size,
                              hipStream_t stream) {
  const float* y    = (const float*)d_in[2];
  const float* H    = (const float*)d_in[3];
  const float* Dinv = (const float*)d_in[4];
  const float* U    = (const float*)d_in[5];
  const float* invM = (const float*)d_in[6];

  float* out     = (float*)d_out;
  float* s_final = out;
  float* traj    = out + BSN;

  char* ws = (char*)d_ws;
  size_t off = 0;
  auto alloc = [&](size_t bytes) -> void* {
    void* p = ws + off;
    off += (bytes + 255) & ~(size_t)255;
    return p;
  };
  bf16_t* U16   = (bf16_t*)alloc((size_t)NDIM * NDIM * 2);  // -> W2rm after megaA
  bf16_t* Dt16  = (bf16_t*)alloc((size_t)NDIM * NDIM * 2);  // -> W4t after megaB
  bf16_t* iMt16 = (bf16_t*)alloc((size_t)NDIM * NDIM * 2);
  bf16_t* H16   = (bf16_t*)alloc((size_t)NDIM * NDIM * 2);  // -> W2t after megaA
  bf16_t* Wrm   = (bf16_t*)alloc((size_t)NDIM * NDIM * 2);
  bf16_t* Wt    = (bf16_t*)alloc((size_t)NDIM * NDIM * 2);
  bf16_t* y16   = (bf16_t*)alloc(BSN * 2);
  bf16_t* yMF16 = (bf16_t*)alloc(BSN * 2);
  bf16_t* c16   = (bf16_t*)alloc(BSN * 2);
  bf16_t* c2_16 = (bf16_t*)alloc(BSN * 2);
  float*  c32   = (float*)alloc(BSN * 4);
  float*  c2_32 = (float*)alloc(BSN * 4);
  float*  c4_32 = (float*)alloc(BSN * 4);
  bf16_t* z0    = (bf16_t*)alloc(2 * BSN * 2);  // x0, x1
  bf16_t* zA    = (bf16_t*)alloc(4 * BSN * 2);  // chains x2..x5
  bf16_t* zB    = (bf16_t*)alloc(4 * BSN * 2);
  int*    bar   = (int*)alloc(256);             // quad_fused phase counters
  bf16_t* W2t   = H16;   // H16 dead after megaA
  bf16_t* W2rm  = U16;   // U16 dead after megaA
  bf16_t* W4t   = Dt16;  // Dt16 dead after megaB

  hipMemsetAsync(bar, 0, 32, stream);           // zero the 5 phase counters

  prep<<<3072, 512, 0, stream>>>(H, U, Dinv, invM, y, H16, U16, Dt16, iMt16, y16, traj);
  megaA<<<384, 512, 0, stream>>>(U16, iMt16, y16, H16, Wrm, Wt, yMF16);
  megaB<<<256, 512, 0, stream>>>(yMF16, iMt16, Dt16, c32, c16, z0);
  megaC<<<512, 512, 0, stream>>>(Wt, Wrm, z0, c16, c32, W2t, W2rm,
                                 traj + BSN, z0 + BSN, c2_32, c2_16);
  megaD<<<384, 512, 0, stream>>>(W2t, z0, c2_16, c2_32, traj + 2 * BSN, traj + 3 * BSN,
                                 zA, c4_32);
  megaE<<<512, 512, 0, stream>>>(W2t, W2rm, zA, c2_32, W4t, traj + 4 * BSN, traj + 5 * BSN, zA);

  // all 5 quad steps in one launch: ping-pong zB/zA, write traj[6..25] + s_final
  quad_fused<<<512, 512, 0, stream>>>(zA, W4t, c4_32, traj + 6 * BSN,
                                      zA, zB, s_final, bar);
}

// Round 2
// 439.606 us; speedup vs baseline: 1.8061x; 1.8061x over previous
//
#include <hip/hip_runtime.h>
#include <hip/hip_bf16.h>

#define NDIM 2048
#define BS   64
#define NM4  (NDIM * NDIM / 4)
#define BSN  ((size_t)BS * NDIM)
#define SMEM_BYTES 69632   // wgemm: 4x16KB pipeline (+ 34.8KB transpose reuse); skinny: 64KB+4KB

typedef __bf16 bf16_t;
typedef __bf16 bf16x4 __attribute__((ext_vector_type(4)));
typedef __bf16 bf16x8 __attribute__((ext_vector_type(8)));
typedef float  f32x4  __attribute__((ext_vector_type(4)));

// Async global->LDS, 16 B per lane.  LDS dest = wave-uniform base + lane*16.
__device__ __forceinline__ void gload16(const void* g, void* lds) {
  __builtin_amdgcn_global_load_lds(
      (const __attribute__((address_space(1))) void*)g,
      (__attribute__((address_space(3))) void*)lds, 16, 0, 0);
}
// 32-bit LDS byte offset of a generic pointer into __shared__.
__device__ __forceinline__ uint32_t lds_off(void* p) {
  return (uint32_t)(uintptr_t)(__attribute__((address_space(3))) void*)p;
}

#define WB4 asm volatile("s_waitcnt vmcnt(4)\n\ts_barrier" ::: "memory")
#define WB2 asm volatile("s_waitcnt vmcnt(2)\n\ts_barrier" ::: "memory")
#define WB0 asm volatile("s_waitcnt vmcnt(0)\n\ts_barrier" ::: "memory")

// ---------------------------------------------------------------------------
// prep (512 thr, 3072 blocks): b<1024 convert H,U (+y, traj0); else 64x64
// fp32->bf16 vectorized transposes of Dinv, invM.
// ---------------------------------------------------------------------------
__global__ __launch_bounds__(512) void prep(
    const float* __restrict__ H, const float* __restrict__ U,
    const float* __restrict__ Dinv, const float* __restrict__ invM,
    const float* __restrict__ y,
    bf16_t* __restrict__ H16, bf16_t* __restrict__ U16,
    bf16_t* __restrict__ Dt, bf16_t* __restrict__ iMt,
    bf16_t* __restrict__ y16, float* __restrict__ traj0) {
  __shared__ bf16_t tile[64][72];
  int b = blockIdx.x, tid = threadIdx.x;
  if (b < 1024) {
#pragma unroll
    for (int i = 0; i < 4; ++i) {
      int idx = b * 2048 + i * 512 + tid;
      const float* src = (idx < NM4) ? H : U;
      bf16_t* dst = (idx < NM4) ? H16 : U16;
      int j = (idx < NM4) ? idx : idx - NM4;
      float4 v = ((const float4*)src)[j];
      bf16x4 o = {(bf16_t)v.x, (bf16_t)v.y, (bf16_t)v.z, (bf16_t)v.w};
      ((bf16x4*)dst)[j] = o;
    }
    int yi = b * 512 + tid;
    if (yi < BS * NDIM / 4) {
      float4 w = ((const float4*)y)[yi];
      bf16x4 o2 = {(bf16_t)w.x, (bf16_t)w.y, (bf16_t)w.z, (bf16_t)w.w};
      ((bf16x4*)y16)[yi] = o2;
      ((float4*)traj0)[yi] = make_float4(0.f, 0.f, 0.f, 0.f);
    }
  } else {
    int id = b - 1024;
    const float* src = (id < 1024) ? Dinv : invM;
    bf16_t* dst = (id < 1024) ? Dt : iMt;
    id &= 1023;
    int bx = id & 31, by = id >> 5;
    int r = tid >> 3, c8 = (tid & 7) * 8;
    const float* sp = src + (size_t)(by * 64 + r) * NDIM + bx * 64 + c8;
    float4 v0 = *(const float4*)sp;
    float4 v1 = *(const float4*)(sp + 4);
    bf16_t* t = &tile[r][c8];
    t[0] = (bf16_t)v0.x; t[1] = (bf16_t)v0.y; t[2] = (bf16_t)v0.z; t[3] = (bf16_t)v0.w;
    t[4] = (bf16_t)v1.x; t[5] = (bf16_t)v1.y; t[6] = (bf16_t)v1.z; t[7] = (bf16_t)v1.w;
    __syncthreads();
    bf16x8 o;
#pragma unroll
    for (int j = 0; j < 8; ++j) o[j] = tile[c8 + j][r];
    *(bf16x8*)(dst + (size_t)(bx * 64 + r) * NDIM + by * 64 + c8) = o;
  }
}

// ---------------------------------------------------------------------------
// wgemm v5: 2048^3 NT GEMM, 512 thr, 128x128 tile, BK=32, 64 chunks, 4-stage
// async pipeline.  Fragment loads are raw asm ds_read_b128 (invisible to
// the compiler's waitcnt pass, so it cannot insert vmcnt(0) drains); data
// readiness enforced by an lgkmcnt(0) asm that redefines the fragment regs.
// XCD-region tile swizzle (neutral in r1, kept: harmless).
// Optional transposed store Ct via LDS round-trip in the freed buffers.
// ---------------------------------------------------------------------------
__device__ __forceinline__ void wgemm_role(
    const bf16_t* __restrict__ A, const bf16_t* __restrict__ Bt,
    bf16_t* __restrict__ C, bf16_t* __restrict__ Ct, int blk, char* smem) {
  int tid = threadIdx.x, lane = tid & 63, wave = tid >> 6;
  int xcd = blk & 7, jj = blk >> 3;
  int m0 = (((xcd >> 1) << 2) + (jj >> 3)) * 128;
  int n0 = (((xcd & 1) << 3) + (jj & 7)) * 128;
  int rl = lane & 15, q = lane >> 4;
  const bf16_t* Ag = A  + (size_t)(m0 + wave * 16 + rl) * NDIM + q * 8;
  const bf16_t* Bg = Bt + (size_t)(n0 + wave * 16 + rl) * NDIM + q * 8;
  char* ldsA = smem + wave * 1024;          // staging slice (this wave) + stage*16384
  char* ldsB = smem + 8192 + wave * 1024;

  int wr2 = (wave & 3) * 2, wc4 = (wave >> 2) * 4;
  uint32_t abase = lds_off(smem) + wr2 * 1024 + lane * 16;
  uint32_t bbase = lds_off(smem) + 8192 + wc4 * 1024 + lane * 16;

  f32x4 acc[2][4];
#pragma unroll
  for (int i = 0; i < 2; ++i)
#pragma unroll
    for (int j = 0; j < 4; ++j) acc[i][j] = (f32x4){0.f, 0.f, 0.f, 0.f};

#define STAGE(s)                                  \
  {                                               \
    int _b = (s) & 3, _k = (s) * 32;              \
    gload16(Ag + _k, ldsA + _b * 16384);          \
    gload16(Bg + _k, ldsB + _b * 16384);          \
  }
#define COMPUTE(bb)                                                            \
  {                                                                            \
    uint32_t av = abase + (bb) * 16384;                                        \
    uint32_t bv = bbase + (bb) * 16384;                                        \
    bf16x8 af0, af1, bg0, bg1, bg2, bg3;                                       \
    asm volatile("ds_read_b128 %0, %1"             : "=v"(af0) : "v"(av));     \
    asm volatile("ds_read_b128 %0, %1 offset:1024" : "=v"(af1) : "v"(av));     \
    asm volatile("ds_read_b128 %0, %1"             : "=v"(bg0) : "v"(bv));     \
    asm volatile("ds_read_b128 %0, %1 offset:1024" : "=v"(bg1) : "v"(bv));     \
    asm volatile("ds_read_b128 %0, %1 offset:2048" : "=v"(bg2) : "v"(bv));     \
    asm volatile("ds_read_b128 %0, %1 offset:3072" : "=v"(bg3) : "v"(bv));     \
    asm volatile("s_waitcnt lgkmcnt(0)"                                        \
                 : "+v"(af0), "+v"(af1), "+v"(bg0), "+v"(bg1), "+v"(bg2),      \
                   "+v"(bg3));                                                 \
    acc[0][0] = __builtin_amdgcn_mfma_f32_16x16x32_bf16(af0, bg0, acc[0][0], 0, 0, 0); \
    acc[0][1] = __builtin_amdgcn_mfma_f32_16x16x32_bf16(af0, bg1, acc[0][1], 0, 0, 0); \
    acc[0][2] = __builtin_amdgcn_mfma_f32_16x16x32_bf16(af0, bg2, acc[0][2], 0, 0, 0); \
    acc[0][3] = __builtin_amdgcn_mfma_f32_16x16x32_bf16(af0, bg3, acc[0][3], 0, 0, 0); \
    acc[1][0] = __builtin_amdgcn_mfma_f32_16x16x32_bf16(af1, bg0, acc[1][0], 0, 0, 0); \
    acc[1][1] = __builtin_amdgcn_mfma_f32_16x16x32_bf16(af1, bg1, acc[1][1], 0, 0, 0); \
    acc[1][2] = __builtin_amdgcn_mfma_f32_16x16x32_bf16(af1, bg2, acc[1][2], 0, 0, 0); \
    acc[1][3] = __builtin_amdgcn_mfma_f32_16x16x32_bf16(af1, bg3, acc[1][3], 0, 0, 0); \
  }

  STAGE(0); STAGE(1); STAGE(2);
  int s = 3;
#pragma unroll 1
  for (int k = 0; k < 60; k += 4) {
    WB4; STAGE(s); ++s; COMPUTE(0);
    WB4; STAGE(s); ++s; COMPUTE(1);
    WB4; STAGE(s); ++s; COMPUTE(2);
    WB4; STAGE(s); ++s; COMPUTE(3);
  }
  WB4; STAGE(63); COMPUTE(0);   // chunk 60
  WB4; COMPUTE(1);              // chunk 61
  WB2; COMPUTE(2);              // chunk 62
  WB0; COMPUTE(3);              // chunk 63
#undef STAGE
#undef COMPUTE

  // normal-orientation store (C[m][n])
#pragma unroll
  for (int i = 0; i < 2; ++i)
#pragma unroll
    for (int j = 0; j < 4; ++j)
#pragma unroll
      for (int r = 0; r < 4; ++r)
        C[(size_t)(m0 + (wr2 + i) * 16 + q * 4 + r) * NDIM + n0 + (wc4 + j) * 16 + rl] =
            (bf16_t)acc[i][j][r];

  // optional transposed store (Ct[n][m]) via LDS round-trip
  if (Ct) {
    __syncthreads();
    bf16_t (*tileT)[136] = (bf16_t(*)[136])smem;   // 128 x 136 x 2 B = 34.8 KB
#pragma unroll
    for (int i = 0; i < 2; ++i)
#pragma unroll
      for (int j = 0; j < 4; ++j)
#pragma unroll
        for (int r = 0; r < 4; ++r)
          tileT[(wc4 + j) * 16 + rl][(wr2 + i) * 16 + q * 4 + r] = (bf16_t)acc[i][j][r];
    __syncthreads();
#pragma unroll
    for (int t = 0; t < 4; ++t) {
      int v = t * 512 + tid, row = v >> 4, c8 = (v & 15) * 8;
      *(bf16x8*)(Ct + (size_t)(n0 + row) * NDIM + m0 + c8) = *(bf16x8*)&tileT[row][c8];
    }
  }
}

// ---------------------------------------------------------------------------
// skinny v3: C[64,16] = add + sign*(A[64,2048] @ Bt^T cols n0..+15).
// Panel (64 KB, fragment order) staged async; waves 0-3 K-half0 / 4-7 K-half1;
// 8 round-robin accumulators; LDS f32 reduction joins halves.
// ---------------------------------------------------------------------------
__device__ __forceinline__ void skinny_role(
    const bf16_t* __restrict__ A, const bf16_t* __restrict__ Bt, int n0, char* smem,
    const float* __restrict__ add, float sign,
    float* o32, float* o32b, bf16_t* o16) {
  int tid = threadIdx.x, lane = tid & 63, wave = tid >> 6;
  int rl = lane & 15, q = lane >> 4;
#pragma unroll
  for (int i = 0; i < 8; ++i) {
    const bf16_t* g = Bt + (size_t)(n0 + rl) * NDIM + (i * 8 + wave) * 32 + q * 8;
    gload16(g, smem + (size_t)(i * 512 + wave * 64) * 16);
  }
  __syncthreads();

  int ms = (wave & 3) * 16, kh = wave >> 2;
  const bf16x8* Ap = (const bf16x8*)(A + (size_t)(ms + rl) * NDIM) + q + kh * 128;
  const bf16x8* Bp = (const bf16x8*)smem + lane + kh * 2048;

  f32x4 acc[8];
#pragma unroll
  for (int i = 0; i < 8; ++i) acc[i] = (f32x4){0.f, 0.f, 0.f, 0.f};
#pragma unroll
  for (int c = 0; c < 32; ++c)
    acc[c & 7] = __builtin_amdgcn_mfma_f32_16x16x32_bf16(Ap[c * 4], Bp[c * 64], acc[c & 7], 0, 0, 0);
  f32x4 s = ((acc[0] + acc[1]) + (acc[2] + acc[3])) + ((acc[4] + acc[5]) + (acc[6] + acc[7]));

  f32x4* red = (f32x4*)(smem + 65536);
  if (wave >= 4) red[(wave & 3) * 64 + lane] = s;
  __syncthreads();
  if (wave < 4) {
    s += red[wave * 64 + lane];
    int mrow = ms + q * 4, col = n0 + rl;
#pragma unroll
    for (int r = 0; r < 4; ++r) {
      size_t o = (size_t)(mrow + r) * NDIM + col;
      float v = sign * s[r];
      if (add) v += add[o];
      if (o32)  o32[o]  = v;
      if (o32b) o32b[o] = v;
      if (o16)  o16[o]  = (bf16_t)v;
    }
  }
}

// --------------------------- mega nodes (512 thr) --------------------------
// A: W = U@invM, dual store Wrm+Wt (256 wgemm) || yMF = y@H^T (128 skinny)
__global__ __launch_bounds__(512, 4) void megaA(
    const bf16_t* __restrict__ U16, const bf16_t* __restrict__ iMt16,
    const bf16_t* __restrict__ y16, const bf16_t* __restrict__ H16,
    bf16_t* __restrict__ Wrm, bf16_t* __restrict__ Wt, bf16_t* __restrict__ yMF16) {
  __shared__ char smem[SMEM_BYTES];
  int b = blockIdx.x;
  if (b < 256) wgemm_role(U16, iMt16, Wrm, Wt, b, smem);
  else         skinny_role(y16, H16, (b - 256) * 16, smem, nullptr, 1.f, nullptr, nullptr, yMF16);
}

// B (light): c = yMF@invM (128) || x0 = yMF@Dinv (128 -> z0)
__global__ __launch_bounds__(512, 4) void megaB(
    const bf16_t* __restrict__ yMF16, const bf16_t* __restrict__ iMt16,
    const bf16_t* __restrict__ Dt16,
    float* __restrict__ c32, bf16_t* __restrict__ c16, bf16_t* __restrict__ z0) {
  __shared__ char smem[SMEM_BYTES];
  int b = blockIdx.x;
  if (b < 128) skinny_role(yMF16, iMt16, b * 16, smem, nullptr, 1.f, c32, nullptr, c16);
  else         skinny_role(yMF16, Dt16, (b - 128) * 16, smem, nullptr, 1.f, nullptr, nullptr, z0);
}

// C: W2 = NT(Wt,Wrm), dual store W2t+W2rm (256) || x1 (128 -> traj[1], z0+BSN)
//    || c2 (128)
__global__ __launch_bounds__(512, 4) void megaC(
    const bf16_t* __restrict__ Wt, const bf16_t* __restrict__ Wrm,
    const bf16_t* __restrict__ z0, const bf16_t* __restrict__ c16,
    const float* __restrict__ c32,
    bf16_t* __restrict__ W2t, bf16_t* __restrict__ W2rm,
    float* __restrict__ traj1, bf16_t* __restrict__ z0b,
    float* __restrict__ c2_32, bf16_t* __restrict__ c2_16) {
  __shared__ char smem[SMEM_BYTES];
  int b = blockIdx.x;
  if (b < 256)      wgemm_role(Wt, Wrm, W2t, W2rm, b, smem);
  else if (b < 384) skinny_role(z0, Wt, (b - 256) * 16, smem, c32, -1.f, traj1, nullptr, z0b);
  else              skinny_role(c16, Wt, (b - 384) * 16, smem, c32, -1.f, c2_32, nullptr, c2_16);
}

// D (light): x2 (128 -> traj[2], zA0) || x3 (128 -> traj[3], zA1) || c4 (128)
__global__ __launch_bounds__(512, 4) void megaD(
    const bf16_t* __restrict__ W2t, const bf16_t* __restrict__ z0,
    const bf16_t* __restrict__ c2_16, const float* __restrict__ c2_32,
    float* __restrict__ traj2, float* __restrict__ traj3,
    bf16_t* __restrict__ zA, float* __restrict__ c4_32) {
  __shared__ char smem[SMEM_BYTES];
  int b = blockIdx.x;
  if (b < 128)      skinny_role(z0, W2t, b * 16, smem, c2_32, 1.f, traj2, nullptr, zA);
  else if (b < 256) skinny_role(z0 + BSN, W2t, (b - 128) * 16, smem, c2_32, 1.f, traj3, nullptr, zA + BSN);
  else              skinny_role(c2_16, W2t, (b - 256) * 16, smem, c2_32, 1.f, c4_32, nullptr, nullptr);
}

// E: W4t = NT(W2t,W2rm) (256) || x4 (128 -> traj[4], zA2) || x5 (128 -> traj[5], zA3)
__global__ __launch_bounds__(512, 4) void megaE(
    const bf16_t* __restrict__ W2t, const bf16_t* __restrict__ W2rm,
    const bf16_t* __restrict__ zA_in, const float* __restrict__ c2_32,
    bf16_t* __restrict__ W4t, float* __restrict__ traj4, float* __restrict__ traj5,
    bf16_t* __restrict__ zA) {
  __shared__ char smem[SMEM_BYTES];
  int b = blockIdx.x;
  if (b < 256)      wgemm_role(W2t, W2rm, W4t, nullptr, b, smem);
  else if (b < 384) skinny_role(zA_in, W2t, (b - 256) * 16, smem, c2_32, 1.f, traj4, nullptr, zA + 2 * BSN);
  else              skinny_role(zA_in + BSN, W2t, (b - 384) * 16, smem, c2_32, 1.f, traj5, nullptr, zA + 3 * BSN);
}

// ---------------------------------------------------------------------------
// quad_fused v2: all 5 quad steps (x_{k+4} = c4 + x_k@W4, 4 chains) in ONE
// launch.  512 blocks = exact residency capacity (69.6 KB LDS -> 2/CU).
// W4t panel staged into LDS once, reused across all 5 steps.
// Barrier v2 (r1 post-mortem: atomicAdd-RMW polling storm cost ~100us/step):
//   - per-CHAIN counters (128 arrivals each, 128 B apart, 4 barriers in
//     parallel; a block only depends on its own chain's writers)
//   - arrival: ONE relaxed fetch_add per block
//   - poll: relaxed atomic LOAD (no RMW, no cacheline ownership) + s_sleep
//   - fences: tid0 only, once per block per step.  Release after
//     __syncthreads (all waves' stores vmcnt-drained into L2 -> fence
//     publishes XCD L2 device-wide); acquire after poll (invalidates this
//     CU's L1 + XCD L2 before reading remote z).  Other waves are covered
//     hardware-wise: caches are per-CU/per-XCD, not per-wave, and
//     __syncthreads orders their accesses around tid0's fences.
// ---------------------------------------------------------------------------
__global__ __launch_bounds__(512, 4) void quad_fused(
    const bf16_t* __restrict__ z_in, const bf16_t* __restrict__ W4t,
    const float* __restrict__ c4_32, float* __restrict__ traj6,
    bf16_t* __restrict__ zping, bf16_t* __restrict__ zpong,
    float* __restrict__ sfin, int* __restrict__ bar) {
  __shared__ char smem[SMEM_BYTES];
  int b = blockIdx.x, ci = b & 3, p = b >> 2;
  int tid = threadIdx.x, lane = tid & 63, wave = tid >> 6;
  int rl = lane & 15, q = lane >> 4;
  int n0 = p * 16;
  // stage W4t panel once (fragment order), reused for all 5 steps
#pragma unroll
  for (int i = 0; i < 8; ++i) {
    const bf16_t* g = W4t + (size_t)(n0 + rl) * NDIM + (i * 8 + wave) * 32 + q * 8;
    gload16(g, smem + (size_t)(i * 512 + wave * 64) * 16);
  }
  __syncthreads();

  int ms = (wave & 3) * 16, kh = wave >> 2;
  const bf16x8* Bp = (const bf16x8*)smem + lane + kh * 2048;
  f32x4* red = (f32x4*)(smem + 65536);
  const bf16_t* zcur = z_in + (size_t)ci * BSN;

#pragma unroll 1
  for (int g = 0; g < 5; ++g) {
    const bf16x8* Ap = (const bf16x8*)(zcur + (size_t)(ms + rl) * NDIM) + q + kh * 128;
    f32x4 acc[8];
#pragma unroll
    for (int i = 0; i < 8; ++i) acc[i] = (f32x4){0.f, 0.f, 0.f, 0.f};
#pragma unroll
    for (int c = 0; c < 32; ++c)
      acc[c & 7] = __builtin_amdgcn_mfma_f32_16x16x32_bf16(Ap[c * 4], Bp[c * 64], acc[c & 7], 0, 0, 0);
    f32x4 s = ((acc[0] + acc[1]) + (acc[2] + acc[3])) + ((acc[4] + acc[5]) + (acc[6] + acc[7]));

    if (wave >= 4) red[(wave & 3) * 64 + lane] = s;
    __syncthreads();
    bf16_t* zn = ((g & 1) ? zping : zpong) + (size_t)ci * BSN;
    if (wave < 4) {
      s += red[wave * 64 + lane];
      int mrow = ms + q * 4, col = n0 + rl;
      float* tj = traj6 + (size_t)(4 * g + ci) * BSN;
#pragma unroll
      for (int r = 0; r < 4; ++r) {
        size_t o = (size_t)(mrow + r) * NDIM + col;
        float v = c4_32[o] + s[r];
        tj[o] = v;
        zn[o] = (bf16_t)v;
        if (g == 4 && ci == 3) sfin[o] = v;
      }
    }
    zcur = zn;
    if (g < 4) {
      __syncthreads();   // all waves' z stores vmcnt-drained into this XCD's L2
      if (tid == 0) {
        __builtin_amdgcn_fence(__ATOMIC_RELEASE, "agent");  // publish XCD L2
        int* ctr = &bar[(g * 4 + ci) * 32];                 // 128B-separated
        __hip_atomic_fetch_add(ctr, 1, __ATOMIC_RELAXED, __HIP_MEMORY_SCOPE_AGENT);
        while (__hip_atomic_load(ctr, __ATOMIC_RELAXED, __HIP_MEMORY_SCOPE_AGENT) < 128)
          __builtin_amdgcn_s_sleep(8);
        __builtin_amdgcn_fence(__ATOMIC_ACQUIRE, "agent");  // inv stale L1/L2
      }
      __syncthreads();
    }
  }
}

// ---------------------------------------------------------------------------
// Host driver: memset + 7 kernel nodes.
// ---------------------------------------------------------------------------
extern "C" void kernel_launch(void* const* d_in, const int* in_sizes, int n_in,
                              void* d_out, int out_size, void* d_ws, size_t ws_size,
                              hipStream_t stream) {
  const float* y    = (const float*)d_in[2];
  const float* H    = (const float*)d_in[3];
  const float* Dinv = (const float*)d_in[4];
  const float* U    = (const float*)d_in[5];
  const float* invM = (const float*)d_in[6];

  float* out     = (float*)d_out;
  float* s_final = out;
  float* traj    = out + BSN;

  char* ws = (char*)d_ws;
  size_t off = 0;
  auto alloc = [&](size_t bytes) -> void* {
    void* p = ws + off;
    off += (bytes + 255) & ~(size_t)255;
    return p;
  };
  bf16_t* U16   = (bf16_t*)alloc((size_t)NDIM * NDIM * 2);  // -> W2rm after megaA
  bf16_t* Dt16  = (bf16_t*)alloc((size_t)NDIM * NDIM * 2);  // -> W4t after megaB
  bf16_t* iMt16 = (bf16_t*)alloc((size_t)NDIM * NDIM * 2);
  bf16_t* H16   = (bf16_t*)alloc((size_t)NDIM * NDIM * 2);  // -> W2t after megaA
  bf16_t* Wrm   = (bf16_t*)alloc((size_t)NDIM * NDIM * 2);
  bf16_t* Wt    = (bf16_t*)alloc((size_t)NDIM * NDIM * 2);
  bf16_t* y16   = (bf16_t*)alloc(BSN * 2);
  bf16_t* yMF16 = (bf16_t*)alloc(BSN * 2);
  bf16_t* c16   = (bf16_t*)alloc(BSN * 2);
  bf16_t* c2_16 = (bf16_t*)alloc(BSN * 2);
  float*  c32   = (float*)alloc(BSN * 4);
  float*  c2_32 = (float*)alloc(BSN * 4);
  float*  c4_32 = (float*)alloc(BSN * 4);
  bf16_t* z0    = (bf16_t*)alloc(2 * BSN * 2);  // x0, x1
  bf16_t* zA    = (bf16_t*)alloc(4 * BSN * 2);  // chains x2..x5
  bf16_t* zB    = (bf16_t*)alloc(4 * BSN * 2);
  int*    bar   = (int*)alloc(4096);            // 16 per-(step,chain) counters
  bf16_t* W2t   = H16;   // H16 dead after megaA
  bf16_t* W2rm  = U16;   // U16 dead after megaA
  bf16_t* W4t   = Dt16;  // Dt16 dead after megaB

  hipMemsetAsync(bar, 0, 4096, stream);

  prep<<<3072, 512, 0, stream>>>(H, U, Dinv, invM, y, H16, U16, Dt16, iMt16, y16, traj);
  megaA<<<384, 512, 0, stream>>>(U16, iMt16, y16, H16, Wrm, Wt, yMF16);
  megaB<<<256, 512, 0, stream>>>(yMF16, iMt16, Dt16, c32, c16, z0);
  megaC<<<512, 512, 0, stream>>>(Wt, Wrm, z0, c16, c32, W2t, W2rm,
                                 traj + BSN, z0 + BSN, c2_32, c2_16);
  megaD<<<384, 512, 0, stream>>>(W2t, z0, c2_16, c2_32, traj + 2 * BSN, traj + 3 * BSN,
                                 zA, c4_32);
  megaE<<<512, 512, 0, stream>>>(W2t, W2rm, zA, c2_32, W4t, traj + 4 * BSN, traj + 5 * BSN, zA);

  // all 5 quad steps in one launch: ping-pong zB/zA, write traj[6..25] + s_final
  quad_fused<<<512, 512, 0, stream>>>(zA, W4t, c4_32, traj + 6 * BSN,
                                      zA, zB, s_final, bar);
}

// Round 3
// 383.169 us; speedup vs baseline: 2.0721x; 1.1473x over previous
//
#include <hip/hip_runtime.h>
#include <hip/hip_bf16.h>

#define NDIM 2048
#define BS   64
#define NM4  (NDIM * NDIM / 4)
#define BSN  ((size_t)BS * NDIM)
#define ZSTRIDE ((size_t)4 * BSN + 2048)   // 4-chain z slab + 4KB pad (blocks HW prefetch bleed)
#define SMEM_BYTES 69632   // wgemm: 4x16KB pipeline (+ 34.8KB transpose reuse); skinny: 64KB+4KB

typedef __bf16 bf16_t;
typedef __bf16 bf16x4 __attribute__((ext_vector_type(4)));
typedef __bf16 bf16x8 __attribute__((ext_vector_type(8)));
typedef float  f32x4  __attribute__((ext_vector_type(4)));

// Async global->LDS, 16 B per lane.  LDS dest = wave-uniform base + lane*16.
__device__ __forceinline__ void gload16(const void* g, void* lds) {
  __builtin_amdgcn_global_load_lds(
      (const __attribute__((address_space(1))) void*)g,
      (__attribute__((address_space(3))) void*)lds, 16, 0, 0);
}
// 32-bit LDS byte offset of a generic pointer into __shared__.
__device__ __forceinline__ uint32_t lds_off(void* p) {
  return (uint32_t)(uintptr_t)(__attribute__((address_space(3))) void*)p;
}
// Agent-coherent (sc1 write-through) bf16 store: visible at the memory-side
// coherence point once vmcnt retires -> no release fence (no buffer_wbl2).
__device__ __forceinline__ void store_agent_bf16(bf16_t* p, float v) {
  union { bf16_t b; unsigned short u; } cv;
  cv.b = (bf16_t)v;
  __hip_atomic_store((unsigned short*)p, cv.u, __ATOMIC_RELAXED, __HIP_MEMORY_SCOPE_AGENT);
}

#define WB4 asm volatile("s_waitcnt vmcnt(4)\n\ts_barrier" ::: "memory")
#define WB2 asm volatile("s_waitcnt vmcnt(2)\n\ts_barrier" ::: "memory")
#define WB0 asm volatile("s_waitcnt vmcnt(0)\n\ts_barrier" ::: "memory")

// ---------------------------------------------------------------------------
// prep (512 thr, 3072 blocks): b<1024 convert H,U (+y, traj0); else 64x64
// fp32->bf16 vectorized transposes of Dinv, invM.
// ---------------------------------------------------------------------------
__global__ __launch_bounds__(512) void prep(
    const float* __restrict__ H, const float* __restrict__ U,
    const float* __restrict__ Dinv, const float* __restrict__ invM,
    const float* __restrict__ y,
    bf16_t* __restrict__ H16, bf16_t* __restrict__ U16,
    bf16_t* __restrict__ Dt, bf16_t* __restrict__ iMt,
    bf16_t* __restrict__ y16, float* __restrict__ traj0) {
  __shared__ bf16_t tile[64][72];
  int b = blockIdx.x, tid = threadIdx.x;
  if (b < 1024) {
#pragma unroll
    for (int i = 0; i < 4; ++i) {
      int idx = b * 2048 + i * 512 + tid;
      const float* src = (idx < NM4) ? H : U;
      bf16_t* dst = (idx < NM4) ? H16 : U16;
      int j = (idx < NM4) ? idx : idx - NM4;
      float4 v = ((const float4*)src)[j];
      bf16x4 o = {(bf16_t)v.x, (bf16_t)v.y, (bf16_t)v.z, (bf16_t)v.w};
      ((bf16x4*)dst)[j] = o;
    }
    int yi = b * 512 + tid;
    if (yi < BS * NDIM / 4) {
      float4 w = ((const float4*)y)[yi];
      bf16x4 o2 = {(bf16_t)w.x, (bf16_t)w.y, (bf16_t)w.z, (bf16_t)w.w};
      ((bf16x4*)y16)[yi] = o2;
      ((float4*)traj0)[yi] = make_float4(0.f, 0.f, 0.f, 0.f);
    }
  } else {
    int id = b - 1024;
    const float* src = (id < 1024) ? Dinv : invM;
    bf16_t* dst = (id < 1024) ? Dt : iMt;
    id &= 1023;
    int bx = id & 31, by = id >> 5;
    int r = tid >> 3, c8 = (tid & 7) * 8;
    const float* sp = src + (size_t)(by * 64 + r) * NDIM + bx * 64 + c8;
    float4 v0 = *(const float4*)sp;
    float4 v1 = *(const float4*)(sp + 4);
    bf16_t* t = &tile[r][c8];
    t[0] = (bf16_t)v0.x; t[1] = (bf16_t)v0.y; t[2] = (bf16_t)v0.z; t[3] = (bf16_t)v0.w;
    t[4] = (bf16_t)v1.x; t[5] = (bf16_t)v1.y; t[6] = (bf16_t)v1.z; t[7] = (bf16_t)v1.w;
    __syncthreads();
    bf16x8 o;
#pragma unroll
    for (int j = 0; j < 8; ++j) o[j] = tile[c8 + j][r];
    *(bf16x8*)(dst + (size_t)(bx * 64 + r) * NDIM + by * 64 + c8) = o;
  }
}

// ---------------------------------------------------------------------------
// wgemm v5: 2048^3 NT GEMM, 512 thr, 128x128 tile, BK=32, 64 chunks, 4-stage
// async pipeline.  Fragment loads are raw asm ds_read_b128 (invisible to
// the compiler's waitcnt pass, so it cannot insert vmcnt(0) drains); data
// readiness enforced by an lgkmcnt(0) asm that redefines the fragment regs.
// XCD-region tile swizzle (neutral in r1, kept: harmless).
// Optional transposed store Ct via LDS round-trip in the freed buffers.
// ---------------------------------------------------------------------------
__device__ __forceinline__ void wgemm_role(
    const bf16_t* __restrict__ A, const bf16_t* __restrict__ Bt,
    bf16_t* __restrict__ C, bf16_t* __restrict__ Ct, int blk, char* smem) {
  int tid = threadIdx.x, lane = tid & 63, wave = tid >> 6;
  int xcd = blk & 7, jj = blk >> 3;
  int m0 = (((xcd >> 1) << 2) + (jj >> 3)) * 128;
  int n0 = (((xcd & 1) << 3) + (jj & 7)) * 128;
  int rl = lane & 15, q = lane >> 4;
  const bf16_t* Ag = A  + (size_t)(m0 + wave * 16 + rl) * NDIM + q * 8;
  const bf16_t* Bg = Bt + (size_t)(n0 + wave * 16 + rl) * NDIM + q * 8;
  char* ldsA = smem + wave * 1024;          // staging slice (this wave) + stage*16384
  char* ldsB = smem + 8192 + wave * 1024;

  int wr2 = (wave & 3) * 2, wc4 = (wave >> 2) * 4;
  uint32_t abase = lds_off(smem) + wr2 * 1024 + lane * 16;
  uint32_t bbase = lds_off(smem) + 8192 + wc4 * 1024 + lane * 16;

  f32x4 acc[2][4];
#pragma unroll
  for (int i = 0; i < 2; ++i)
#pragma unroll
    for (int j = 0; j < 4; ++j) acc[i][j] = (f32x4){0.f, 0.f, 0.f, 0.f};

#define STAGE(s)                                  \
  {                                               \
    int _b = (s) & 3, _k = (s) * 32;              \
    gload16(Ag + _k, ldsA + _b * 16384);          \
    gload16(Bg + _k, ldsB + _b * 16384);          \
  }
#define COMPUTE(bb)                                                            \
  {                                                                            \
    uint32_t av = abase + (bb) * 16384;                                        \
    uint32_t bv = bbase + (bb) * 16384;                                        \
    bf16x8 af0, af1, bg0, bg1, bg2, bg3;                                       \
    asm volatile("ds_read_b128 %0, %1"             : "=v"(af0) : "v"(av));     \
    asm volatile("ds_read_b128 %0, %1 offset:1024" : "=v"(af1) : "v"(av));     \
    asm volatile("ds_read_b128 %0, %1"             : "=v"(bg0) : "v"(bv));     \
    asm volatile("ds_read_b128 %0, %1 offset:1024" : "=v"(bg1) : "v"(bv));     \
    asm volatile("ds_read_b128 %0, %1 offset:2048" : "=v"(bg2) : "v"(bv));     \
    asm volatile("ds_read_b128 %0, %1 offset:3072" : "=v"(bg3) : "v"(bv));     \
    asm volatile("s_waitcnt lgkmcnt(0)"                                        \
                 : "+v"(af0), "+v"(af1), "+v"(bg0), "+v"(bg1), "+v"(bg2),      \
                   "+v"(bg3));                                                 \
    acc[0][0] = __builtin_amdgcn_mfma_f32_16x16x32_bf16(af0, bg0, acc[0][0], 0, 0, 0); \
    acc[0][1] = __builtin_amdgcn_mfma_f32_16x16x32_bf16(af0, bg1, acc[0][1], 0, 0, 0); \
    acc[0][2] = __builtin_amdgcn_mfma_f32_16x16x32_bf16(af0, bg2, acc[0][2], 0, 0, 0); \
    acc[0][3] = __builtin_amdgcn_mfma_f32_16x16x32_bf16(af0, bg3, acc[0][3], 0, 0, 0); \
    acc[1][0] = __builtin_amdgcn_mfma_f32_16x16x32_bf16(af1, bg0, acc[1][0], 0, 0, 0); \
    acc[1][1] = __builtin_amdgcn_mfma_f32_16x16x32_bf16(af1, bg1, acc[1][1], 0, 0, 0); \
    acc[1][2] = __builtin_amdgcn_mfma_f32_16x16x32_bf16(af1, bg2, acc[1][2], 0, 0, 0); \
    acc[1][3] = __builtin_amdgcn_mfma_f32_16x16x32_bf16(af1, bg3, acc[1][3], 0, 0, 0); \
  }

  STAGE(0); STAGE(1); STAGE(2);
  int s = 3;
#pragma unroll 1
  for (int k = 0; k < 60; k += 4) {
    WB4; STAGE(s); ++s; COMPUTE(0);
    WB4; STAGE(s); ++s; COMPUTE(1);
    WB4; STAGE(s); ++s; COMPUTE(2);
    WB4; STAGE(s); ++s; COMPUTE(3);
  }
  WB4; STAGE(63); COMPUTE(0);   // chunk 60
  WB4; COMPUTE(1);              // chunk 61
  WB2; COMPUTE(2);              // chunk 62
  WB0; COMPUTE(3);              // chunk 63
#undef STAGE
#undef COMPUTE

  // normal-orientation store (C[m][n])
#pragma unroll
  for (int i = 0; i < 2; ++i)
#pragma unroll
    for (int j = 0; j < 4; ++j)
#pragma unroll
      for (int r = 0; r < 4; ++r)
        C[(size_t)(m0 + (wr2 + i) * 16 + q * 4 + r) * NDIM + n0 + (wc4 + j) * 16 + rl] =
            (bf16_t)acc[i][j][r];

  // optional transposed store (Ct[n][m]) via LDS round-trip
  if (Ct) {
    __syncthreads();
    bf16_t (*tileT)[136] = (bf16_t(*)[136])smem;   // 128 x 136 x 2 B = 34.8 KB
#pragma unroll
    for (int i = 0; i < 2; ++i)
#pragma unroll
      for (int j = 0; j < 4; ++j)
#pragma unroll
        for (int r = 0; r < 4; ++r)
          tileT[(wc4 + j) * 16 + rl][(wr2 + i) * 16 + q * 4 + r] = (bf16_t)acc[i][j][r];
    __syncthreads();
#pragma unroll
    for (int t = 0; t < 4; ++t) {
      int v = t * 512 + tid, row = v >> 4, c8 = (v & 15) * 8;
      *(bf16x8*)(Ct + (size_t)(n0 + row) * NDIM + m0 + c8) = *(bf16x8*)&tileT[row][c8];
    }
  }
}

// ---------------------------------------------------------------------------
// skinny v3: C[64,16] = add + sign*(A[64,2048] @ Bt^T cols n0..+15).
// Panel (64 KB, fragment order) staged async; waves 0-3 K-half0 / 4-7 K-half1;
// 8 round-robin accumulators; LDS f32 reduction joins halves.
// ---------------------------------------------------------------------------
__device__ __forceinline__ void skinny_role(
    const bf16_t* __restrict__ A, const bf16_t* __restrict__ Bt, int n0, char* smem,
    const float* __restrict__ add, float sign,
    float* o32, float* o32b, bf16_t* o16) {
  int tid = threadIdx.x, lane = tid & 63, wave = tid >> 6;
  int rl = lane & 15, q = lane >> 4;
#pragma unroll
  for (int i = 0; i < 8; ++i) {
    const bf16_t* g = Bt + (size_t)(n0 + rl) * NDIM + (i * 8 + wave) * 32 + q * 8;
    gload16(g, smem + (size_t)(i * 512 + wave * 64) * 16);
  }
  __syncthreads();

  int ms = (wave & 3) * 16, kh = wave >> 2;
  const bf16x8* Ap = (const bf16x8*)(A + (size_t)(ms + rl) * NDIM) + q + kh * 128;
  const bf16x8* Bp = (const bf16x8*)smem + lane + kh * 2048;

  f32x4 acc[8];
#pragma unroll
  for (int i = 0; i < 8; ++i) acc[i] = (f32x4){0.f, 0.f, 0.f, 0.f};
#pragma unroll
  for (int c = 0; c < 32; ++c)
    acc[c & 7] = __builtin_amdgcn_mfma_f32_16x16x32_bf16(Ap[c * 4], Bp[c * 64], acc[c & 7], 0, 0, 0);
  f32x4 s = ((acc[0] + acc[1]) + (acc[2] + acc[3])) + ((acc[4] + acc[5]) + (acc[6] + acc[7]));

  f32x4* red = (f32x4*)(smem + 65536);
  if (wave >= 4) red[(wave & 3) * 64 + lane] = s;
  __syncthreads();
  if (wave < 4) {
    s += red[wave * 64 + lane];
    int mrow = ms + q * 4, col = n0 + rl;
#pragma unroll
    for (int r = 0; r < 4; ++r) {
      size_t o = (size_t)(mrow + r) * NDIM + col;
      float v = sign * s[r];
      if (add) v += add[o];
      if (o32)  o32[o]  = v;
      if (o32b) o32b[o] = v;
      if (o16)  o16[o]  = (bf16_t)v;
    }
  }
}

// --------------------------- mega nodes (512 thr) --------------------------
// A: W = U@invM, dual store Wrm+Wt (256 wgemm) || yMF = y@H^T (128 skinny)
__global__ __launch_bounds__(512, 4) void megaA(
    const bf16_t* __restrict__ U16, const bf16_t* __restrict__ iMt16,
    const bf16_t* __restrict__ y16, const bf16_t* __restrict__ H16,
    bf16_t* __restrict__ Wrm, bf16_t* __restrict__ Wt, bf16_t* __restrict__ yMF16) {
  __shared__ char smem[SMEM_BYTES];
  int b = blockIdx.x;
  if (b < 256) wgemm_role(U16, iMt16, Wrm, Wt, b, smem);
  else         skinny_role(y16, H16, (b - 256) * 16, smem, nullptr, 1.f, nullptr, nullptr, yMF16);
}

// B (light): c = yMF@invM (128) || x0 = yMF@Dinv (128 -> z0)
__global__ __launch_bounds__(512, 4) void megaB(
    const bf16_t* __restrict__ yMF16, const bf16_t* __restrict__ iMt16,
    const bf16_t* __restrict__ Dt16,
    float* __restrict__ c32, bf16_t* __restrict__ c16, bf16_t* __restrict__ z0) {
  __shared__ char smem[SMEM_BYTES];
  int b = blockIdx.x;
  if (b < 128) skinny_role(yMF16, iMt16, b * 16, smem, nullptr, 1.f, c32, nullptr, c16);
  else         skinny_role(yMF16, Dt16, (b - 128) * 16, smem, nullptr, 1.f, nullptr, nullptr, z0);
}

// C: W2 = NT(Wt,Wrm), dual store W2t+W2rm (256) || x1 (128 -> traj[1], z0+BSN)
//    || c2 (128)
__global__ __launch_bounds__(512, 4) void megaC(
    const bf16_t* __restrict__ Wt, const bf16_t* __restrict__ Wrm,
    const bf16_t* __restrict__ z0, const bf16_t* __restrict__ c16,
    const float* __restrict__ c32,
    bf16_t* __restrict__ W2t, bf16_t* __restrict__ W2rm,
    float* __restrict__ traj1, bf16_t* __restrict__ z0b,
    float* __restrict__ c2_32, bf16_t* __restrict__ c2_16) {
  __shared__ char smem[SMEM_BYTES];
  int b = blockIdx.x;
  if (b < 256)      wgemm_role(Wt, Wrm, W2t, W2rm, b, smem);
  else if (b < 384) skinny_role(z0, Wt, (b - 256) * 16, smem, c32, -1.f, traj1, nullptr, z0b);
  else              skinny_role(c16, Wt, (b - 384) * 16, smem, c32, -1.f, c2_32, nullptr, c2_16);
}

// D (light): x2 (128 -> traj[2], zA0) || x3 (128 -> traj[3], zA1) || c4 (128)
__global__ __launch_bounds__(512, 4) void megaD(
    const bf16_t* __restrict__ W2t, const bf16_t* __restrict__ z0,
    const bf16_t* __restrict__ c2_16, const float* __restrict__ c2_32,
    float* __restrict__ traj2, float* __restrict__ traj3,
    bf16_t* __restrict__ zA, float* __restrict__ c4_32) {
  __shared__ char smem[SMEM_BYTES];
  int b = blockIdx.x;
  if (b < 128)      skinny_role(z0, W2t, b * 16, smem, c2_32, 1.f, traj2, nullptr, zA);
  else if (b < 256) skinny_role(z0 + BSN, W2t, (b - 128) * 16, smem, c2_32, 1.f, traj3, nullptr, zA + BSN);
  else              skinny_role(c2_16, W2t, (b - 256) * 16, smem, c2_32, 1.f, c4_32, nullptr, nullptr);
}

// E: W4t = NT(W2t,W2rm) (256) || x4 (128 -> traj[4], zA2) || x5 (128 -> traj[5], zA3)
__global__ __launch_bounds__(512, 4) void megaE(
    const bf16_t* __restrict__ W2t, const bf16_t* __restrict__ W2rm,
    const bf16_t* __restrict__ zA_in, const float* __restrict__ c2_32,
    bf16_t* __restrict__ W4t, float* __restrict__ traj4, float* __restrict__ traj5,
    bf16_t* __restrict__ zA) {
  __shared__ char smem[SMEM_BYTES];
  int b = blockIdx.x;
  if (b < 256)      wgemm_role(W2t, W2rm, W4t, nullptr, b, smem);
  else if (b < 384) skinny_role(zA_in, W2t, (b - 256) * 16, smem, c2_32, 1.f, traj4, nullptr, zA + 2 * BSN);
  else              skinny_role(zA_in + BSN, W2t, (b - 384) * 16, smem, c2_32, 1.f, traj5, nullptr, zA + 3 * BSN);
}

// ---------------------------------------------------------------------------
// quad_fused v3: all 5 quad steps (x_{k+4} = c4 + x_k@W4, 4 chains) in ONE
// launch, FENCE-FREE.  512 blocks = exact residency capacity (2/CU).
// W4t panel staged into LDS once, reused across all 5 steps.
// r2 post-mortem: the agent release/acquire fences cost ~35us/step each
// (buffer_wbl2/buffer_inv = full 4MiB L2 tag-walk per XCD).  v3 removes ALL
// fences:
//   - z hand-off values are written with agent-scope relaxed atomic stores
//     (sc1 write-through): visible at the memory-side coherence point once
//     vmcnt retires, which __syncthreads already enforces before s_barrier.
//   - each step writes a FRESH 4KB-padded buffer zs[g]: no cache in the
//     system can hold a stale line for an address nobody has touched this
//     dispatch (kernel-start acquire wipes prior-replay lines), so consumer
//     reads are plain cached loads (L2-served after first touch).
//   - barrier: one relaxed fetch_add per block per step on a per-(step,chain)
//     counter + relaxed-load poll (no RMW storm, no ownership ping-pong).
// Correctness depends only on co-residency (proven: v1/v2 passed) and the
// coherence argument above -- NOT on block->XCD placement.
// ---------------------------------------------------------------------------
__global__ __launch_bounds__(512, 4) void quad_fused(
    const bf16_t* __restrict__ z_in, const bf16_t* __restrict__ W4t,
    const float* __restrict__ c4_32, float* __restrict__ traj6,
    bf16_t* __restrict__ zsteps, float* __restrict__ sfin, int* __restrict__ bar) {
  __shared__ char smem[SMEM_BYTES];
  int b = blockIdx.x, ci = b & 3, p = b >> 2;
  int tid = threadIdx.x, lane = tid & 63, wave = tid >> 6;
  int rl = lane & 15, q = lane >> 4;
  int n0 = p * 16;
  // stage W4t panel once (fragment order), reused for all 5 steps
#pragma unroll
  for (int i = 0; i < 8; ++i) {
    const bf16_t* g = W4t + (size_t)(n0 + rl) * NDIM + (i * 8 + wave) * 32 + q * 8;
    gload16(g, smem + (size_t)(i * 512 + wave * 64) * 16);
  }
  __syncthreads();

  int ms = (wave & 3) * 16, kh = wave >> 2;
  const bf16x8* Bp = (const bf16x8*)smem + lane + kh * 2048;
  f32x4* red = (f32x4*)(smem + 65536);
  const bf16_t* zcur = z_in + (size_t)ci * BSN;

#pragma unroll 1
  for (int g = 0; g < 5; ++g) {
    const bf16x8* Ap = (const bf16x8*)(zcur + (size_t)(ms + rl) * NDIM) + q + kh * 128;
    f32x4 acc[8];
#pragma unroll
    for (int i = 0; i < 8; ++i) acc[i] = (f32x4){0.f, 0.f, 0.f, 0.f};
#pragma unroll
    for (int c = 0; c < 32; ++c)
      acc[c & 7] = __builtin_amdgcn_mfma_f32_16x16x32_bf16(Ap[c * 4], Bp[c * 64], acc[c & 7], 0, 0, 0);
    f32x4 s = ((acc[0] + acc[1]) + (acc[2] + acc[3])) + ((acc[4] + acc[5]) + (acc[6] + acc[7]));

    if (wave >= 4) red[(wave & 3) * 64 + lane] = s;
    __syncthreads();
    bf16_t* zn = zsteps + (size_t)g * ZSTRIDE + (size_t)ci * BSN;  // fresh buffer
    if (wave < 4) {
      s += red[wave * 64 + lane];
      int mrow = ms + q * 4, col = n0 + rl;
      float* tj = traj6 + (size_t)(4 * g + ci) * BSN;
#pragma unroll
      for (int r = 0; r < 4; ++r) {
        size_t o = (size_t)(mrow + r) * NDIM + col;
        float v = c4_32[o] + s[r];
        tj[o] = v;                         // output: normal store, flushed at kernel end
        if (g < 4) store_agent_bf16(&zn[o], v);   // hand-off: coherent write-through
        if (g == 4 && ci == 3) sfin[o] = v;
      }
    }
    if (g < 4) {
      __syncthreads();   // emits s_waitcnt vmcnt(0) first: all sc1 stores at coherence point
      if (tid == 0) {
        int* ctr = &bar[(g * 4 + ci) * 32];  // 128B-separated per (step,chain)
        __hip_atomic_fetch_add(ctr, 1, __ATOMIC_RELAXED, __HIP_MEMORY_SCOPE_AGENT);
        while (__hip_atomic_load(ctr, __ATOMIC_RELAXED, __HIP_MEMORY_SCOPE_AGENT) < 128)
          __builtin_amdgcn_s_sleep(1);
        asm volatile("" ::: "memory");     // no acquire fence needed: no stale lines exist
      }
      __syncthreads();
      zcur = zn;
    }
  }
}

// ---------------------------------------------------------------------------
// Host driver: memset + 7 kernel nodes.
// ---------------------------------------------------------------------------
extern "C" void kernel_launch(void* const* d_in, const int* in_sizes, int n_in,
                              void* d_out, int out_size, void* d_ws, size_t ws_size,
                              hipStream_t stream) {
  const float* y    = (const float*)d_in[2];
  const float* H    = (const float*)d_in[3];
  const float* Dinv = (const float*)d_in[4];
  const float* U    = (const float*)d_in[5];
  const float* invM = (const float*)d_in[6];

  float* out     = (float*)d_out;
  float* s_final = out;
  float* traj    = out + BSN;

  char* ws = (char*)d_ws;
  size_t off = 0;
  auto alloc = [&](size_t bytes) -> void* {
    void* p = ws + off;
    off += (bytes + 255) & ~(size_t)255;
    return p;
  };
  bf16_t* U16   = (bf16_t*)alloc((size_t)NDIM * NDIM * 2);  // -> W2rm after megaA
  bf16_t* Dt16  = (bf16_t*)alloc((size_t)NDIM * NDIM * 2);  // -> W4t after megaB
  bf16_t* iMt16 = (bf16_t*)alloc((size_t)NDIM * NDIM * 2);
  bf16_t* H16   = (bf16_t*)alloc((size_t)NDIM * NDIM * 2);  // -> W2t after megaA
  bf16_t* Wrm   = (bf16_t*)alloc((size_t)NDIM * NDIM * 2);
  bf16_t* Wt    = (bf16_t*)alloc((size_t)NDIM * NDIM * 2);
  bf16_t* y16   = (bf16_t*)alloc(BSN * 2);
  bf16_t* yMF16 = (bf16_t*)alloc(BSN * 2);
  bf16_t* c16   = (bf16_t*)alloc(BSN * 2);
  bf16_t* c2_16 = (bf16_t*)alloc(BSN * 2);
  float*  c32   = (float*)alloc(BSN * 4);
  float*  c2_32 = (float*)alloc(BSN * 4);
  float*  c4_32 = (float*)alloc(BSN * 4);
  bf16_t* z0    = (bf16_t*)alloc(2 * BSN * 2);          // x0, x1
  bf16_t* zA    = (bf16_t*)alloc(4 * BSN * 2);          // chains x2..x5 (quad input)
  bf16_t* zsteps= (bf16_t*)alloc(5 * ZSTRIDE * 2);      // 5 fresh per-step hand-off slabs
  int*    bar   = (int*)alloc(4096);                    // 16 per-(step,chain) counters
  bf16_t* W2t   = H16;   // H16 dead after megaA
  bf16_t* W2rm  = U16;   // U16 dead after megaA
  bf16_t* W4t   = Dt16;  // Dt16 dead after megaB

  hipMemsetAsync(bar, 0, 4096, stream);

  prep<<<3072, 512, 0, stream>>>(H, U, Dinv, invM, y, H16, U16, Dt16, iMt16, y16, traj);
  megaA<<<384, 512, 0, stream>>>(U16, iMt16, y16, H16, Wrm, Wt, yMF16);
  megaB<<<256, 512, 0, stream>>>(yMF16, iMt16, Dt16, c32, c16, z0);
  megaC<<<512, 512, 0, stream>>>(Wt, Wrm, z0, c16, c32, W2t, W2rm,
                                 traj + BSN, z0 + BSN, c2_32, c2_16);
  megaD<<<384, 512, 0, stream>>>(W2t, z0, c2_16, c2_32, traj + 2 * BSN, traj + 3 * BSN,
                                 zA, c4_32);
  megaE<<<512, 512, 0, stream>>>(W2t, W2rm, zA, c2_32, W4t, traj + 4 * BSN, traj + 5 * BSN, zA);

  // all 5 quad steps in one fence-free launch: fresh slab per step,
  // writes traj[6..25] + s_final
  quad_fused<<<512, 512, 0, stream>>>(zA, W4t, c4_32, traj + 6 * BSN,
                                      zsteps, s_final, bar);
}

// Round 4
// 328.533 us; speedup vs baseline: 2.4167x; 1.1663x over previous
//
#include <hip/hip_runtime.h>
#include <hip/hip_bf16.h>

#define NDIM 2048
#define BS   64
#define NM4  (NDIM * NDIM / 4)
#define BSN  ((size_t)BS * NDIM)
#define ZSTRIDE ((size_t)4 * BSN + 2048)   // 4-chain z slab + 4KB pad
#define SMEM_BYTES 71680   // 64KB panel + 4KB reduce + 2KB pack; 2 blocks/CU (143KB<160KB)

typedef __bf16 bf16_t;
typedef __bf16 bf16x4 __attribute__((ext_vector_type(4)));
typedef __bf16 bf16x8 __attribute__((ext_vector_type(8)));
typedef float  f32x4  __attribute__((ext_vector_type(4)));
typedef unsigned long long u64_t;

// Async global->LDS, 16 B per lane.  LDS dest = wave-uniform base + lane*16.
__device__ __forceinline__ void gload16(const void* g, void* lds) {
  __builtin_amdgcn_global_load_lds(
      (const __attribute__((address_space(1))) void*)g,
      (__attribute__((address_space(3))) void*)lds, 16, 0, 0);
}
// 32-bit LDS byte offset of a generic pointer into __shared__.
__device__ __forceinline__ uint32_t lds_off(void* p) {
  return (uint32_t)(uintptr_t)(__attribute__((address_space(3))) void*)p;
}

#define WB4 asm volatile("s_waitcnt vmcnt(4)\n\ts_barrier" ::: "memory")
#define WB2 asm volatile("s_waitcnt vmcnt(2)\n\ts_barrier" ::: "memory")
#define WB0 asm volatile("s_waitcnt vmcnt(0)\n\ts_barrier" ::: "memory")

// ---------------------------------------------------------------------------
// prep (512 thr, 3072 blocks): b<1024 convert H,U (+y, traj0); else 64x64
// fp32->bf16 vectorized transposes of Dinv, invM.
// ---------------------------------------------------------------------------
__global__ __launch_bounds__(512) void prep(
    const float* __restrict__ H, const float* __restrict__ U,
    const float* __restrict__ Dinv, const float* __restrict__ invM,
    const float* __restrict__ y,
    bf16_t* __restrict__ H16, bf16_t* __restrict__ U16,
    bf16_t* __restrict__ Dt, bf16_t* __restrict__ iMt,
    bf16_t* __restrict__ y16, float* __restrict__ traj0) {
  __shared__ bf16_t tile[64][72];
  int b = blockIdx.x, tid = threadIdx.x;
  if (b < 1024) {
#pragma unroll
    for (int i = 0; i < 4; ++i) {
      int idx = b * 2048 + i * 512 + tid;
      const float* src = (idx < NM4) ? H : U;
      bf16_t* dst = (idx < NM4) ? H16 : U16;
      int j = (idx < NM4) ? idx : idx - NM4;
      float4 v = ((const float4*)src)[j];
      bf16x4 o = {(bf16_t)v.x, (bf16_t)v.y, (bf16_t)v.z, (bf16_t)v.w};
      ((bf16x4*)dst)[j] = o;
    }
    int yi = b * 512 + tid;
    if (yi < BS * NDIM / 4) {
      float4 w = ((const float4*)y)[yi];
      bf16x4 o2 = {(bf16_t)w.x, (bf16_t)w.y, (bf16_t)w.z, (bf16_t)w.w};
      ((bf16x4*)y16)[yi] = o2;
      ((float4*)traj0)[yi] = make_float4(0.f, 0.f, 0.f, 0.f);
    }
  } else {
    int id = b - 1024;
    const float* src = (id < 1024) ? Dinv : invM;
    bf16_t* dst = (id < 1024) ? Dt : iMt;
    id &= 1023;
    int bx = id & 31, by = id >> 5;
    int r = tid >> 3, c8 = (tid & 7) * 8;
    const float* sp = src + (size_t)(by * 64 + r) * NDIM + bx * 64 + c8;
    float4 v0 = *(const float4*)sp;
    float4 v1 = *(const float4*)(sp + 4);
    bf16_t* t = &tile[r][c8];
    t[0] = (bf16_t)v0.x; t[1] = (bf16_t)v0.y; t[2] = (bf16_t)v0.z; t[3] = (bf16_t)v0.w;
    t[4] = (bf16_t)v1.x; t[5] = (bf16_t)v1.y; t[6] = (bf16_t)v1.z; t[7] = (bf16_t)v1.w;
    __syncthreads();
    bf16x8 o;
#pragma unroll
    for (int j = 0; j < 8; ++j) o[j] = tile[c8 + j][r];
    *(bf16x8*)(dst + (size_t)(bx * 64 + r) * NDIM + by * 64 + c8) = o;
  }
}

// ---------------------------------------------------------------------------
// wgemm v5: 2048^3 NT GEMM, 512 thr, 128x128 tile, BK=32, 64 chunks, 4-stage
// async pipeline.  Fragment loads are raw asm ds_read_b128 (invisible to
// the compiler's waitcnt pass); readiness via lgkmcnt(0) asm.
// XCD-region tile swizzle (neutral, kept).  Optional transposed store Ct.
// ---------------------------------------------------------------------------
__device__ __forceinline__ void wgemm_role(
    const bf16_t* __restrict__ A, const bf16_t* __restrict__ Bt,
    bf16_t* __restrict__ C, bf16_t* __restrict__ Ct, int blk, char* smem) {
  int tid = threadIdx.x, lane = tid & 63, wave = tid >> 6;
  int xcd = blk & 7, jj = blk >> 3;
  int m0 = (((xcd >> 1) << 2) + (jj >> 3)) * 128;
  int n0 = (((xcd & 1) << 3) + (jj & 7)) * 128;
  int rl = lane & 15, q = lane >> 4;
  const bf16_t* Ag = A  + (size_t)(m0 + wave * 16 + rl) * NDIM + q * 8;
  const bf16_t* Bg = Bt + (size_t)(n0 + wave * 16 + rl) * NDIM + q * 8;
  char* ldsA = smem + wave * 1024;          // staging slice (this wave) + stage*16384
  char* ldsB = smem + 8192 + wave * 1024;

  int wr2 = (wave & 3) * 2, wc4 = (wave >> 2) * 4;
  uint32_t abase = lds_off(smem) + wr2 * 1024 + lane * 16;
  uint32_t bbase = lds_off(smem) + 8192 + wc4 * 1024 + lane * 16;

  f32x4 acc[2][4];
#pragma unroll
  for (int i = 0; i < 2; ++i)
#pragma unroll
    for (int j = 0; j < 4; ++j) acc[i][j] = (f32x4){0.f, 0.f, 0.f, 0.f};

#define STAGE(s)                                  \
  {                                               \
    int _b = (s) & 3, _k = (s) * 32;              \
    gload16(Ag + _k, ldsA + _b * 16384);          \
    gload16(Bg + _k, ldsB + _b * 16384);          \
  }
#define COMPUTE(bb)                                                            \
  {                                                                            \
    uint32_t av = abase + (bb) * 16384;                                        \
    uint32_t bv = bbase + (bb) * 16384;                                        \
    bf16x8 af0, af1, bg0, bg1, bg2, bg3;                                       \
    asm volatile("ds_read_b128 %0, %1"             : "=v"(af0) : "v"(av));     \
    asm volatile("ds_read_b128 %0, %1 offset:1024" : "=v"(af1) : "v"(av));     \
    asm volatile("ds_read_b128 %0, %1"             : "=v"(bg0) : "v"(bv));     \
    asm volatile("ds_read_b128 %0, %1 offset:1024" : "=v"(bg1) : "v"(bv));     \
    asm volatile("ds_read_b128 %0, %1 offset:2048" : "=v"(bg2) : "v"(bv));     \
    asm volatile("ds_read_b128 %0, %1 offset:3072" : "=v"(bg3) : "v"(bv));     \
    asm volatile("s_waitcnt lgkmcnt(0)"                                        \
                 : "+v"(af0), "+v"(af1), "+v"(bg0), "+v"(bg1), "+v"(bg2),      \
                   "+v"(bg3));                                                 \
    acc[0][0] = __builtin_amdgcn_mfma_f32_16x16x32_bf16(af0, bg0, acc[0][0], 0, 0, 0); \
    acc[0][1] = __builtin_amdgcn_mfma_f32_16x16x32_bf16(af0, bg1, acc[0][1], 0, 0, 0); \
    acc[0][2] = __builtin_amdgcn_mfma_f32_16x16x32_bf16(af0, bg2, acc[0][2], 0, 0, 0); \
    acc[0][3] = __builtin_amdgcn_mfma_f32_16x16x32_bf16(af0, bg3, acc[0][3], 0, 0, 0); \
    acc[1][0] = __builtin_amdgcn_mfma_f32_16x16x32_bf16(af1, bg0, acc[1][0], 0, 0, 0); \
    acc[1][1] = __builtin_amdgcn_mfma_f32_16x16x32_bf16(af1, bg1, acc[1][1], 0, 0, 0); \
    acc[1][2] = __builtin_amdgcn_mfma_f32_16x16x32_bf16(af1, bg2, acc[1][2], 0, 0, 0); \
    acc[1][3] = __builtin_amdgcn_mfma_f32_16x16x32_bf16(af1, bg3, acc[1][3], 0, 0, 0); \
  }

  STAGE(0); STAGE(1); STAGE(2);
  int s = 3;
#pragma unroll 1
  for (int k = 0; k < 60; k += 4) {
    WB4; STAGE(s); ++s; COMPUTE(0);
    WB4; STAGE(s); ++s; COMPUTE(1);
    WB4; STAGE(s); ++s; COMPUTE(2);
    WB4; STAGE(s); ++s; COMPUTE(3);
  }
  WB4; STAGE(63); COMPUTE(0);   // chunk 60
  WB4; COMPUTE(1);              // chunk 61
  WB2; COMPUTE(2);              // chunk 62
  WB0; COMPUTE(3);              // chunk 63
#undef STAGE
#undef COMPUTE

  // normal-orientation store (C[m][n])
#pragma unroll
  for (int i = 0; i < 2; ++i)
#pragma unroll
    for (int j = 0; j < 4; ++j)
#pragma unroll
      for (int r = 0; r < 4; ++r)
        C[(size_t)(m0 + (wr2 + i) * 16 + q * 4 + r) * NDIM + n0 + (wc4 + j) * 16 + rl] =
            (bf16_t)acc[i][j][r];

  // optional transposed store (Ct[n][m]) via LDS round-trip
  if (Ct) {
    __syncthreads();
    bf16_t (*tileT)[136] = (bf16_t(*)[136])smem;   // 128 x 136 x 2 B = 34.8 KB
#pragma unroll
    for (int i = 0; i < 2; ++i)
#pragma unroll
      for (int j = 0; j < 4; ++j)
#pragma unroll
        for (int r = 0; r < 4; ++r)
          tileT[(wc4 + j) * 16 + rl][(wr2 + i) * 16 + q * 4 + r] = (bf16_t)acc[i][j][r];
    __syncthreads();
#pragma unroll
    for (int t = 0; t < 4; ++t) {
      int v = t * 512 + tid, row = v >> 4, c8 = (v & 15) * 8;
      *(bf16x8*)(Ct + (size_t)(n0 + row) * NDIM + m0 + c8) = *(bf16x8*)&tileT[row][c8];
    }
  }
}

// ---------------------------------------------------------------------------
// skinny v4: C[64,16] = add + sign*(A[64,2048] @ Bt^T cols n0..+15).
// Panel (64 KB, fragment order) staged async; waves 0-3 K-half0 / 4-7 K-half1;
// 8 round-robin accumulators; LDS f32 reduction joins halves.
// o16blk: optional BLOCKED bf16 store (panel-contiguous [p][64][16]) used for
// the quad-chain hand-off layout.
// ---------------------------------------------------------------------------
__device__ __forceinline__ void skinny_role(
    const bf16_t* __restrict__ A, const bf16_t* __restrict__ Bt, int n0, char* smem,
    const float* __restrict__ add, float sign,
    float* o32, float* o32b, bf16_t* o16, bf16_t* o16blk) {
  int tid = threadIdx.x, lane = tid & 63, wave = tid >> 6;
  int rl = lane & 15, q = lane >> 4;
#pragma unroll
  for (int i = 0; i < 8; ++i) {
    const bf16_t* g = Bt + (size_t)(n0 + rl) * NDIM + (i * 8 + wave) * 32 + q * 8;
    gload16(g, smem + (size_t)(i * 512 + wave * 64) * 16);
  }
  __syncthreads();

  int ms = (wave & 3) * 16, kh = wave >> 2;
  const bf16x8* Ap = (const bf16x8*)(A + (size_t)(ms + rl) * NDIM) + q + kh * 128;
  const bf16x8* Bp = (const bf16x8*)smem + lane + kh * 2048;

  f32x4 acc[8];
#pragma unroll
  for (int i = 0; i < 8; ++i) acc[i] = (f32x4){0.f, 0.f, 0.f, 0.f};
#pragma unroll
  for (int c = 0; c < 32; ++c)
    acc[c & 7] = __builtin_amdgcn_mfma_f32_16x16x32_bf16(Ap[c * 4], Bp[c * 64], acc[c & 7], 0, 0, 0);
  f32x4 s = ((acc[0] + acc[1]) + (acc[2] + acc[3])) + ((acc[4] + acc[5]) + (acc[6] + acc[7]));

  f32x4* red = (f32x4*)(smem + 65536);
  if (wave >= 4) red[(wave & 3) * 64 + lane] = s;
  __syncthreads();
  if (wave < 4) {
    s += red[wave * 64 + lane];
    int mrow = ms + q * 4, col = n0 + rl;
#pragma unroll
    for (int r = 0; r < 4; ++r) {
      size_t o = (size_t)(mrow + r) * NDIM + col;
      float v = sign * s[r];
      if (add) v += add[o];
      if (o32)  o32[o]  = v;
      if (o32b) o32b[o] = v;
      if (o16)  o16[o]  = (bf16_t)v;
      if (o16blk) o16blk[(size_t)(n0 >> 4) * 1024 + (mrow + r) * 16 + rl] = (bf16_t)v;
    }
  }
}

// --------------------------- mega nodes (512 thr) --------------------------
// A: W = U@invM, dual store Wrm+Wt (256 wgemm) || yMF = y@H^T (128 skinny)
__global__ __launch_bounds__(512, 4) void megaA(
    const bf16_t* __restrict__ U16, const bf16_t* __restrict__ iMt16,
    const bf16_t* __restrict__ y16, const bf16_t* __restrict__ H16,
    bf16_t* __restrict__ Wrm, bf16_t* __restrict__ Wt, bf16_t* __restrict__ yMF16) {
  __shared__ char smem[SMEM_BYTES];
  int b = blockIdx.x;
  if (b < 256) wgemm_role(U16, iMt16, Wrm, Wt, b, smem);
  else         skinny_role(y16, H16, (b - 256) * 16, smem, nullptr, 1.f,
                           nullptr, nullptr, yMF16, nullptr);
}

// B (light): c = yMF@invM (128) || x0 = yMF@Dinv (128 -> z0)
__global__ __launch_bounds__(512, 4) void megaB(
    const bf16_t* __restrict__ yMF16, const bf16_t* __restrict__ iMt16,
    const bf16_t* __restrict__ Dt16,
    float* __restrict__ c32, bf16_t* __restrict__ c16, bf16_t* __restrict__ z0) {
  __shared__ char smem[SMEM_BYTES];
  int b = blockIdx.x;
  if (b < 128) skinny_role(yMF16, iMt16, b * 16, smem, nullptr, 1.f, c32, nullptr, c16, nullptr);
  else         skinny_role(yMF16, Dt16, (b - 128) * 16, smem, nullptr, 1.f, nullptr, nullptr, z0, nullptr);
}

// C: W2 = NT(Wt,Wrm), dual store W2t+W2rm (256) || x1 (128 -> traj[1], z0+BSN)
//    || c2 (128)
__global__ __launch_bounds__(512, 4) void megaC(
    const bf16_t* __restrict__ Wt, const bf16_t* __restrict__ Wrm,
    const bf16_t* __restrict__ z0, const bf16_t* __restrict__ c16,
    const float* __restrict__ c32,
    bf16_t* __restrict__ W2t, bf16_t* __restrict__ W2rm,
    float* __restrict__ traj1, bf16_t* __restrict__ z0b,
    float* __restrict__ c2_32, bf16_t* __restrict__ c2_16) {
  __shared__ char smem[SMEM_BYTES];
  int b = blockIdx.x;
  if (b < 256)      wgemm_role(Wt, Wrm, W2t, W2rm, b, smem);
  else if (b < 384) skinny_role(z0, Wt, (b - 256) * 16, smem, c32, -1.f, traj1, nullptr, z0b, nullptr);
  else              skinny_role(c16, Wt, (b - 384) * 16, smem, c32, -1.f, c2_32, nullptr, c2_16, nullptr);
}

// D (light): x2 (128 -> traj[2], zA row + blk) || x3 (128 -> traj[3]) || c4 (128)
// x2/x3 dual-stored: row-major (megaE's A-operand) + blocked (quad hand-off).
__global__ __launch_bounds__(512, 4) void megaD(
    const bf16_t* __restrict__ W2t, const bf16_t* __restrict__ z0,
    const bf16_t* __restrict__ c2_16, const float* __restrict__ c2_32,
    float* __restrict__ traj2, float* __restrict__ traj3,
    bf16_t* __restrict__ zA, bf16_t* __restrict__ zAblk, float* __restrict__ c4_32) {
  __shared__ char smem[SMEM_BYTES];
  int b = blockIdx.x;
  if (b < 128)      skinny_role(z0, W2t, b * 16, smem, c2_32, 1.f, traj2, nullptr, zA, zAblk);
  else if (b < 256) skinny_role(z0 + BSN, W2t, (b - 128) * 16, smem, c2_32, 1.f, traj3, nullptr,
                                zA + BSN, zAblk + BSN);
  else              skinny_role(c2_16, W2t, (b - 256) * 16, smem, c2_32, 1.f, c4_32, nullptr,
                                nullptr, nullptr);
}

// E: W4t = NT(W2t,W2rm) (256) || x4 (128 -> traj[4], blk chain2) || x5 (128 -> traj[5], blk chain3)
__global__ __launch_bounds__(512, 4) void megaE(
    const bf16_t* __restrict__ W2t, const bf16_t* __restrict__ W2rm,
    const bf16_t* __restrict__ zA_in, const float* __restrict__ c2_32,
    bf16_t* __restrict__ W4t, float* __restrict__ traj4, float* __restrict__ traj5,
    bf16_t* __restrict__ zAblk) {
  __shared__ char smem[SMEM_BYTES];
  int b = blockIdx.x;
  if (b < 256)      wgemm_role(W2t, W2rm, W4t, nullptr, b, smem);
  else if (b < 384) skinny_role(zA_in, W2t, (b - 256) * 16, smem, c2_32, 1.f, traj4, nullptr,
                                nullptr, zAblk + 2 * BSN);
  else              skinny_role(zA_in + BSN, W2t, (b - 384) * 16, smem, c2_32, 1.f, traj5, nullptr,
                                nullptr, zAblk + 3 * BSN);
}

// ---------------------------------------------------------------------------
// quad_fused v4: all 5 quad steps (x_{k+4} = c4 + x_k@W4, 4 chains) in ONE
// fence-free launch.  512 blocks = exact residency capacity (2/CU).
// W4t panel staged into LDS once, reused across all 5 steps.
// r3 post-mortem: the hand-off was 2-byte agent-scope (sc1 write-through)
// stores at 4KB row stride -> 32B fabric segments that cannot combine in any
// cache; vmcnt(0) drain of ~32K tiny transactions per step dominated.
// v4: BLOCKED hand-off layout zblk[p][64][16] (panel-contiguous):
//   - producer packs its 64x16 panel in LDS (2KB), then 128 threads emit it
//     as fully-coalesced 16B/lane agent-scope stores (full fabric lines).
//   - consumer A-fragment (8 consecutive k of one row) = one 16B slice of
//     one panel: panel = kh*64 + 2c + (q>>1), col = (q&1)*8 -> bf16x8 loads.
//   - barrier: relaxed per-(step,chain) fetch_add + relaxed-load poll,
//     zero fences (v3's fresh-buffer-per-step argument unchanged).
// ---------------------------------------------------------------------------
__global__ __launch_bounds__(512, 4) void quad_fused(
    const bf16_t* __restrict__ zblk_in, const bf16_t* __restrict__ W4t,
    const float* __restrict__ c4_32, float* __restrict__ traj6,
    bf16_t* __restrict__ zsteps, float* __restrict__ sfin, int* __restrict__ bar) {
  __shared__ char smem[SMEM_BYTES];
  int b = blockIdx.x, ci = b & 3, p = b >> 2;
  int tid = threadIdx.x, lane = tid & 63, wave = tid >> 6;
  int rl = lane & 15, q = lane >> 4;
  int n0 = p * 16;
  // stage W4t panel once (fragment order), reused for all 5 steps
#pragma unroll
  for (int i = 0; i < 8; ++i) {
    const bf16_t* g = W4t + (size_t)(n0 + rl) * NDIM + (i * 8 + wave) * 32 + q * 8;
    gload16(g, smem + (size_t)(i * 512 + wave * 64) * 16);
  }
  __syncthreads();

  int ms = (wave & 3) * 16, kh = wave >> 2;
  const bf16x8* Bp = (const bf16x8*)smem + lane + kh * 2048;
  f32x4*  red  = (f32x4*)(smem + 65536);   // 4 KB
  bf16_t* pack = (bf16_t*)(smem + 69632);  // 2 KB panel pack
  const bf16_t* zcur = zblk_in + (size_t)ci * BSN;
  // per-thread blocked A offset in bf16x8 units:
  //   elem addr = panel*1024 + row*16 + (q&1)*8, panel = kh*64 + 2c + (q>>1)
  int aoff = (ms + rl) * 2 + (q & 1) + (q >> 1) * 128 + kh * 8192;

#pragma unroll 1
  for (int g = 0; g < 5; ++g) {
    const bf16x8* Az = (const bf16x8*)zcur + aoff;
    f32x4 acc[8];
#pragma unroll
    for (int i = 0; i < 8; ++i) acc[i] = (f32x4){0.f, 0.f, 0.f, 0.f};
#pragma unroll
    for (int c = 0; c < 32; ++c)
      acc[c & 7] = __builtin_amdgcn_mfma_f32_16x16x32_bf16(Az[c * 256], Bp[c * 64], acc[c & 7], 0, 0, 0);
    f32x4 s = ((acc[0] + acc[1]) + (acc[2] + acc[3])) + ((acc[4] + acc[5]) + (acc[6] + acc[7]));

    if (wave >= 4) red[(wave & 3) * 64 + lane] = s;
    __syncthreads();
    bf16_t* zn = zsteps + (size_t)g * ZSTRIDE + (size_t)ci * BSN;  // fresh blocked buffer
    if (wave < 4) {
      s += red[wave * 64 + lane];
      int mrow = ms + q * 4, col = n0 + rl;
      float* tj = traj6 + (size_t)(4 * g + ci) * BSN;
#pragma unroll
      for (int r = 0; r < 4; ++r) {
        size_t o = (size_t)(mrow + r) * NDIM + col;
        float v = c4_32[o] + s[r];
        tj[o] = v;                         // output: plain write-back store
        if (g == 4 && ci == 3) sfin[o] = v;
        if (g < 4) pack[(mrow + r) * 16 + rl] = (bf16_t)v;
      }
    }
    if (g < 4) {
      __syncthreads();                     // panel pack complete in LDS
      if (tid < 128) {                     // coalesced 16B/lane agent stores
        int row = tid >> 1, hf = tid & 1;
        const u64_t* src = (const u64_t*)pack + row * 4 + hf * 2;
        u64_t* dst = (u64_t*)(zn + (size_t)p * 1024) + row * 4 + hf * 2;
        __hip_atomic_store(dst,     src[0], __ATOMIC_RELAXED, __HIP_MEMORY_SCOPE_AGENT);
        __hip_atomic_store(dst + 1, src[1], __ATOMIC_RELAXED, __HIP_MEMORY_SCOPE_AGENT);
      }
      __syncthreads();   // emits s_waitcnt vmcnt(0): all sc1 stores at coherence point
      if (tid == 0) {
        int* ctr = &bar[(g * 4 + ci) * 32];  // 128B-separated per (step,chain)
        __hip_atomic_fetch_add(ctr, 1, __ATOMIC_RELAXED, __HIP_MEMORY_SCOPE_AGENT);
        while (__hip_atomic_load(ctr, __ATOMIC_RELAXED, __HIP_MEMORY_SCOPE_AGENT) < 128)
          __builtin_amdgcn_s_sleep(1);
        asm volatile("" ::: "memory");     // no acquire fence: fresh buffer, no stale lines
      }
      __syncthreads();
      zcur = zn;
    }
  }
}

// ---------------------------------------------------------------------------
// Host driver: memset + 7 kernel nodes.
// ---------------------------------------------------------------------------
extern "C" void kernel_launch(void* const* d_in, const int* in_sizes, int n_in,
                              void* d_out, int out_size, void* d_ws, size_t ws_size,
                              hipStream_t stream) {
  const float* y    = (const float*)d_in[2];
  const float* H    = (const float*)d_in[3];
  const float* Dinv = (const float*)d_in[4];
  const float* U    = (const float*)d_in[5];
  const float* invM = (const float*)d_in[6];

  float* out     = (float*)d_out;
  float* s_final = out;
  float* traj    = out + BSN;

  char* ws = (char*)d_ws;
  size_t off = 0;
  auto alloc = [&](size_t bytes) -> void* {
    void* p = ws + off;
    off += (bytes + 255) & ~(size_t)255;
    return p;
  };
  bf16_t* U16   = (bf16_t*)alloc((size_t)NDIM * NDIM * 2);  // -> W2rm after megaA
  bf16_t* Dt16  = (bf16_t*)alloc((size_t)NDIM * NDIM * 2);  // -> W4t after megaB
  bf16_t* iMt16 = (bf16_t*)alloc((size_t)NDIM * NDIM * 2);
  bf16_t* H16   = (bf16_t*)alloc((size_t)NDIM * NDIM * 2);  // -> W2t after megaA
  bf16_t* Wrm   = (bf16_t*)alloc((size_t)NDIM * NDIM * 2);
  bf16_t* Wt    = (bf16_t*)alloc((size_t)NDIM * NDIM * 2);
  bf16_t* y16   = (bf16_t*)alloc(BSN * 2);
  bf16_t* yMF16 = (bf16_t*)alloc(BSN * 2);
  bf16_t* c16   = (bf16_t*)alloc(BSN * 2);
  bf16_t* c2_16 = (bf16_t*)alloc(BSN * 2);
  float*  c32   = (float*)alloc(BSN * 4);
  float*  c2_32 = (float*)alloc(BSN * 4);
  float*  c4_32 = (float*)alloc(BSN * 4);
  bf16_t* z0    = (bf16_t*)alloc(2 * BSN * 2);          // x0, x1 (row-major)
  bf16_t* zA    = (bf16_t*)alloc(2 * BSN * 2);          // x2, x3 row-major (megaE A-operand)
  bf16_t* zAblk = (bf16_t*)alloc(4 * BSN * 2);          // x2..x5 blocked (quad input)
  bf16_t* zsteps= (bf16_t*)alloc(5 * ZSTRIDE * 2);      // 5 fresh per-step blocked slabs
  int*    bar   = (int*)alloc(4096);                    // 16 per-(step,chain) counters
  bf16_t* W2t   = H16;   // H16 dead after megaA
  bf16_t* W2rm  = U16;   // U16 dead after megaA
  bf16_t* W4t   = Dt16;  // Dt16 dead after megaB

  hipMemsetAsync(bar, 0, 4096, stream);

  prep<<<3072, 512, 0, stream>>>(H, U, Dinv, invM, y, H16, U16, Dt16, iMt16, y16, traj);
  megaA<<<384, 512, 0, stream>>>(U16, iMt16, y16, H16, Wrm, Wt, yMF16);
  megaB<<<256, 512, 0, stream>>>(yMF16, iMt16, Dt16, c32, c16, z0);
  megaC<<<512, 512, 0, stream>>>(Wt, Wrm, z0, c16, c32, W2t, W2rm,
                                 traj + BSN, z0 + BSN, c2_32, c2_16);
  megaD<<<384, 512, 0, stream>>>(W2t, z0, c2_16, c2_32, traj + 2 * BSN, traj + 3 * BSN,
                                 zA, zAblk, c4_32);
  megaE<<<512, 512, 0, stream>>>(W2t, W2rm, zA, c2_32, W4t, traj + 4 * BSN, traj + 5 * BSN,
                                 zAblk);

  // all 5 quad steps in one fence-free launch: fresh blocked slab per step,
  // writes traj[6..25] + s_final
  quad_fused<<<512, 512, 0, stream>>>(zAblk, W4t, c4_32, traj + 6 * BSN,
                                      zsteps, s_final, bar);
}

// Round 5
// 285.141 us; speedup vs baseline: 2.7844x; 1.1522x over previous
//
#include <hip/hip_runtime.h>
#include <hip/hip_bf16.h>

#define NDIM 2048
#define BS   64
#define NM4  (NDIM * NDIM / 4)
#define BSN  ((size_t)BS * NDIM)
#define ZSTRIDE ((size_t)4 * BSN + 2048)   // 4-chain z slab + 4KB pad
#define SMEM_BYTES 71680   // 64KB panel/pipeline + 4KB reduce + 2KB pack; 2 blocks/CU

typedef __bf16 bf16_t;
typedef __bf16 bf16x4 __attribute__((ext_vector_type(4)));
typedef __bf16 bf16x8 __attribute__((ext_vector_type(8)));
typedef float  f32x4  __attribute__((ext_vector_type(4)));
typedef unsigned long long u64_t;

// Async global->LDS, 16 B per lane.  LDS dest = wave-uniform base + lane*16.
__device__ __forceinline__ void gload16(const void* g, void* lds) {
  __builtin_amdgcn_global_load_lds(
      (const __attribute__((address_space(1))) void*)g,
      (__attribute__((address_space(3))) void*)lds, 16, 0, 0);
}
// 32-bit LDS byte offset of a generic pointer into __shared__.
__device__ __forceinline__ uint32_t lds_off(void* p) {
  return (uint32_t)(uintptr_t)(__attribute__((address_space(3))) void*)p;
}

// ---------------------------------------------------------------------------
// prep (512 thr, 3072 blocks): b<1024 convert H,U (+y, traj0); else 64x64
// fp32->bf16 vectorized transposes of Dinv, invM.
// ---------------------------------------------------------------------------
__global__ __launch_bounds__(512) void prep(
    const float* __restrict__ H, const float* __restrict__ U,
    const float* __restrict__ Dinv, const float* __restrict__ invM,
    const float* __restrict__ y,
    bf16_t* __restrict__ H16, bf16_t* __restrict__ U16,
    bf16_t* __restrict__ Dt, bf16_t* __restrict__ iMt,
    bf16_t* __restrict__ y16, float* __restrict__ traj0) {
  __shared__ bf16_t tile[64][72];
  int b = blockIdx.x, tid = threadIdx.x;
  if (b < 1024) {
#pragma unroll
    for (int i = 0; i < 4; ++i) {
      int idx = b * 2048 + i * 512 + tid;
      const float* src = (idx < NM4) ? H : U;
      bf16_t* dst = (idx < NM4) ? H16 : U16;
      int j = (idx < NM4) ? idx : idx - NM4;
      float4 v = ((const float4*)src)[j];
      bf16x4 o = {(bf16_t)v.x, (bf16_t)v.y, (bf16_t)v.z, (bf16_t)v.w};
      ((bf16x4*)dst)[j] = o;
    }
    int yi = b * 512 + tid;
    if (yi < BS * NDIM / 4) {
      float4 w = ((const float4*)y)[yi];
      bf16x4 o2 = {(bf16_t)w.x, (bf16_t)w.y, (bf16_t)w.z, (bf16_t)w.w};
      ((bf16x4*)y16)[yi] = o2;
      ((float4*)traj0)[yi] = make_float4(0.f, 0.f, 0.f, 0.f);
    }
  } else {
    int id = b - 1024;
    const float* src = (id < 1024) ? Dinv : invM;
    bf16_t* dst = (id < 1024) ? Dt : iMt;
    id &= 1023;
    int bx = id & 31, by = id >> 5;
    int r = tid >> 3, c8 = (tid & 7) * 8;
    const float* sp = src + (size_t)(by * 64 + r) * NDIM + bx * 64 + c8;
    float4 v0 = *(const float4*)sp;
    float4 v1 = *(const float4*)(sp + 4);
    bf16_t* t = &tile[r][c8];
    t[0] = (bf16_t)v0.x; t[1] = (bf16_t)v0.y; t[2] = (bf16_t)v0.z; t[3] = (bf16_t)v0.w;
    t[4] = (bf16_t)v1.x; t[5] = (bf16_t)v1.y; t[6] = (bf16_t)v1.z; t[7] = (bf16_t)v1.w;
    __syncthreads();
    bf16x8 o;
#pragma unroll
    for (int j = 0; j < 8; ++j) o[j] = tile[c8 + j][r];
    *(bf16x8*)(dst + (size_t)(bx * 64 + r) * NDIM + by * 64 + c8) = o;
  }
}

// ---------------------------------------------------------------------------
// wgemm v6 (producer-consumer): 2048^3 NT GEMM, 512 thr, 128x128 tile, BK=32,
// 64 chunks, 4-stage async pipeline.
// r4 post-mortem: v5 was LDS-BW-bound (~1800cyc/chunk; 128KB LDS traffic/CU
// /chunk at ~85B/cyc; MfmaUtil 13%).  v6 cuts LDS reads 1.5x:
//   - waves 0-3: pure CONSUMERS, each owns a 64x64 quadrant (4x4 MFMAs per
//     chunk from 8 ds_read_b128 -> FLOP/LDS-byte 21 -> 32).
//   - waves 4-7: pure PRODUCERS, counted-vmcnt staging (4 gload16/chunk each,
//     vmcnt(8) steady-state, never 0 until tail).  No lgkm waits.
// Barrier counts matched exactly: producers 3-stage prologue + 61 loop + 3
// tail = 64; consumers 64.  LDS slice layout: addr(row,k) = (row>>4)*1024 +
// (row&15)*64 + (k>>3)*16  (A at stage*16384, B at +8192).
// ---------------------------------------------------------------------------
__device__ __forceinline__ void wgemm_role(
    const bf16_t* __restrict__ A, const bf16_t* __restrict__ Bt,
    bf16_t* __restrict__ C, bf16_t* __restrict__ Ct, int blk, char* smem) {
  int tid = threadIdx.x, lane = tid & 63, wave = tid >> 6;
  int xcd = blk & 7, jj = blk >> 3;
  int m0 = (((xcd >> 1) << 2) + (jj >> 3)) * 128;
  int n0 = (((xcd & 1) << 3) + (jj & 7)) * 128;
  int rl = lane & 15, q = lane >> 4;

  if (wave >= 4) {
    // ---------------- producer: stage A,B chunks, counted vmcnt ----------
    int pw = wave - 4;                       // 0..3: slices {2pw,2pw+1} of A and B
    int pr = lane >> 2, pk = (lane & 3) * 8; // 16 rows x 4 k-groups per slice
    const bf16_t* PA0 = A  + (size_t)(m0 + pw * 32 + pr) * NDIM + pk;
    const bf16_t* PA1 = PA0 + 16 * NDIM;
    const bf16_t* PB0 = Bt + (size_t)(n0 + pw * 32 + pr) * NDIM + pk;
    const bf16_t* PB1 = PB0 + 16 * NDIM;
#define PSTAGE(s)                                          \
    {                                                      \
      int _b = (s) & 3, _k = (s) * 32;                     \
      char* _st = smem + _b * 16384 + pw * 2048;           \
      gload16(PA0 + _k, _st);                              \
      gload16(PA1 + _k, _st + 1024);                       \
      gload16(PB0 + _k, _st + 8192);                       \
      gload16(PB1 + _k, _st + 9216);                       \
    }
    PSTAGE(0); PSTAGE(1); PSTAGE(2);
#pragma unroll 1
    for (int k = 0; k < 61; ++k) {
      asm volatile("s_waitcnt vmcnt(8)\n\ts_barrier" ::: "memory");
      PSTAGE(k + 3);
    }
    asm volatile("s_waitcnt vmcnt(8)\n\ts_barrier" ::: "memory");  // chunk 61
    asm volatile("s_waitcnt vmcnt(4)\n\ts_barrier" ::: "memory");  // chunk 62
    asm volatile("s_waitcnt vmcnt(0)\n\ts_barrier" ::: "memory");  // chunk 63
#undef PSTAGE
    // fall through to (optional) Ct cooperative copy below
    if (Ct) {
      __syncthreads();   // consumers writing tileT
      __syncthreads();
      bf16_t (*tileT)[136] = (bf16_t(*)[136])smem;
#pragma unroll
      for (int t = 0; t < 4; ++t) {
        int v = t * 512 + tid, row = v >> 4, c8 = (v & 15) * 8;
        *(bf16x8*)(Ct + (size_t)(n0 + row) * NDIM + m0 + c8) = *(bf16x8*)&tileT[row][c8];
      }
    }
    return;
  }

  // ------------------ consumer: 64x64 quadrant, 16 MFMA/chunk -------------
  int wr = wave & 1, wc = wave >> 1;
  uint32_t abase = lds_off(smem) + wr * 4096 + rl * 64 + q * 16;
  uint32_t bbase = lds_off(smem) + 8192 + wc * 4096 + rl * 64 + q * 16;

  f32x4 acc[4][4];
#pragma unroll
  for (int i = 0; i < 4; ++i)
#pragma unroll
    for (int j = 0; j < 4; ++j) acc[i][j] = (f32x4){0.f, 0.f, 0.f, 0.f};

#define CCOMPUTE(bb)                                                           \
  {                                                                            \
    uint32_t av = abase + (bb) * 16384;                                        \
    uint32_t bv = bbase + (bb) * 16384;                                        \
    bf16x8 a0, a1, a2, a3, b0, b1, b2, b3;                                     \
    asm volatile("ds_read_b128 %0, %1"             : "=v"(a0) : "v"(av));      \
    asm volatile("ds_read_b128 %0, %1 offset:1024" : "=v"(a1) : "v"(av));      \
    asm volatile("ds_read_b128 %0, %1 offset:2048" : "=v"(a2) : "v"(av));      \
    asm volatile("ds_read_b128 %0, %1 offset:3072" : "=v"(a3) : "v"(av));      \
    asm volatile("ds_read_b128 %0, %1"             : "=v"(b0) : "v"(bv));      \
    asm volatile("ds_read_b128 %0, %1 offset:1024" : "=v"(b1) : "v"(bv));      \
    asm volatile("ds_read_b128 %0, %1 offset:2048" : "=v"(b2) : "v"(bv));      \
    asm volatile("ds_read_b128 %0, %1 offset:3072" : "=v"(b3) : "v"(bv));      \
    asm volatile("s_waitcnt lgkmcnt(0)"                                        \
                 : "+v"(a0), "+v"(a1), "+v"(a2), "+v"(a3), "+v"(b0),           \
                   "+v"(b1), "+v"(b2), "+v"(b3));                              \
    acc[0][0] = __builtin_amdgcn_mfma_f32_16x16x32_bf16(a0, b0, acc[0][0], 0, 0, 0); \
    acc[0][1] = __builtin_amdgcn_mfma_f32_16x16x32_bf16(a0, b1, acc[0][1], 0, 0, 0); \
    acc[0][2] = __builtin_amdgcn_mfma_f32_16x16x32_bf16(a0, b2, acc[0][2], 0, 0, 0); \
    acc[0][3] = __builtin_amdgcn_mfma_f32_16x16x32_bf16(a0, b3, acc[0][3], 0, 0, 0); \
    acc[1][0] = __builtin_amdgcn_mfma_f32_16x16x32_bf16(a1, b0, acc[1][0], 0, 0, 0); \
    acc[1][1] = __builtin_amdgcn_mfma_f32_16x16x32_bf16(a1, b1, acc[1][1], 0, 0, 0); \
    acc[1][2] = __builtin_amdgcn_mfma_f32_16x16x32_bf16(a1, b2, acc[1][2], 0, 0, 0); \
    acc[1][3] = __builtin_amdgcn_mfma_f32_16x16x32_bf16(a1, b3, acc[1][3], 0, 0, 0); \
    acc[2][0] = __builtin_amdgcn_mfma_f32_16x16x32_bf16(a2, b0, acc[2][0], 0, 0, 0); \
    acc[2][1] = __builtin_amdgcn_mfma_f32_16x16x32_bf16(a2, b1, acc[2][1], 0, 0, 0); \
    acc[2][2] = __builtin_amdgcn_mfma_f32_16x16x32_bf16(a2, b2, acc[2][2], 0, 0, 0); \
    acc[2][3] = __builtin_amdgcn_mfma_f32_16x16x32_bf16(a2, b3, acc[2][3], 0, 0, 0); \
    acc[3][0] = __builtin_amdgcn_mfma_f32_16x16x32_bf16(a3, b0, acc[3][0], 0, 0, 0); \
    acc[3][1] = __builtin_amdgcn_mfma_f32_16x16x32_bf16(a3, b1, acc[3][1], 0, 0, 0); \
    acc[3][2] = __builtin_amdgcn_mfma_f32_16x16x32_bf16(a3, b2, acc[3][2], 0, 0, 0); \
    acc[3][3] = __builtin_amdgcn_mfma_f32_16x16x32_bf16(a3, b3, acc[3][3], 0, 0, 0); \
  }

#pragma unroll 1
  for (int k = 0; k < 64; k += 4) {
    asm volatile("s_barrier" ::: "memory"); CCOMPUTE(0);
    asm volatile("s_barrier" ::: "memory"); CCOMPUTE(1);
    asm volatile("s_barrier" ::: "memory"); CCOMPUTE(2);
    asm volatile("s_barrier" ::: "memory"); CCOMPUTE(3);
  }
#undef CCOMPUTE

  // normal-orientation store (C[m][n]); C/D layout: col=lane&15, row=q*4+reg
#pragma unroll
  for (int i = 0; i < 4; ++i)
#pragma unroll
    for (int j = 0; j < 4; ++j)
#pragma unroll
      for (int r = 0; r < 4; ++r)
        C[(size_t)(m0 + wr * 64 + i * 16 + q * 4 + r) * NDIM + n0 + wc * 64 + j * 16 + rl] =
            (bf16_t)acc[i][j][r];

  // optional transposed store (Ct[n][m]) via LDS round-trip
  if (Ct) {
    __syncthreads();
    bf16_t (*tileT)[136] = (bf16_t(*)[136])smem;   // 128 x 136 x 2 B = 34.8 KB
#pragma unroll
    for (int i = 0; i < 4; ++i)
#pragma unroll
      for (int j = 0; j < 4; ++j)
#pragma unroll
        for (int r = 0; r < 4; ++r)
          tileT[wc * 64 + j * 16 + rl][wr * 64 + i * 16 + q * 4 + r] = (bf16_t)acc[i][j][r];
    __syncthreads();
#pragma unroll
    for (int t = 0; t < 4; ++t) {
      int v = t * 512 + tid, row = v >> 4, c8 = (v & 15) * 8;
      *(bf16x8*)(Ct + (size_t)(n0 + row) * NDIM + m0 + c8) = *(bf16x8*)&tileT[row][c8];
    }
  }
}

// ---------------------------------------------------------------------------
// skinny v4: C[64,16] = add + sign*(A[64,2048] @ Bt^T cols n0..+15).
// Panel (64 KB, fragment order) staged async; waves 0-3 K-half0 / 4-7 K-half1;
// 8 round-robin accumulators; LDS f32 reduction joins halves.
// o16blk: optional BLOCKED bf16 store (panel-contiguous [p][64][16]).
// ---------------------------------------------------------------------------
__device__ __forceinline__ void skinny_role(
    const bf16_t* __restrict__ A, const bf16_t* __restrict__ Bt, int n0, char* smem,
    const float* __restrict__ add, float sign,
    float* o32, float* o32b, bf16_t* o16, bf16_t* o16blk) {
  int tid = threadIdx.x, lane = tid & 63, wave = tid >> 6;
  int rl = lane & 15, q = lane >> 4;
#pragma unroll
  for (int i = 0; i < 8; ++i) {
    const bf16_t* g = Bt + (size_t)(n0 + rl) * NDIM + (i * 8 + wave) * 32 + q * 8;
    gload16(g, smem + (size_t)(i * 512 + wave * 64) * 16);
  }
  __syncthreads();

  int ms = (wave & 3) * 16, kh = wave >> 2;
  const bf16x8* Ap = (const bf16x8*)(A + (size_t)(ms + rl) * NDIM) + q + kh * 128;
  const bf16x8* Bp = (const bf16x8*)smem + lane + kh * 2048;

  f32x4 acc[8];
#pragma unroll
  for (int i = 0; i < 8; ++i) acc[i] = (f32x4){0.f, 0.f, 0.f, 0.f};
#pragma unroll
  for (int c = 0; c < 32; ++c)
    acc[c & 7] = __builtin_amdgcn_mfma_f32_16x16x32_bf16(Ap[c * 4], Bp[c * 64], acc[c & 7], 0, 0, 0);
  f32x4 s = ((acc[0] + acc[1]) + (acc[2] + acc[3])) + ((acc[4] + acc[5]) + (acc[6] + acc[7]));

  f32x4* red = (f32x4*)(smem + 65536);
  if (wave >= 4) red[(wave & 3) * 64 + lane] = s;
  __syncthreads();
  if (wave < 4) {
    s += red[wave * 64 + lane];
    int mrow = ms + q * 4, col = n0 + rl;
#pragma unroll
    for (int r = 0; r < 4; ++r) {
      size_t o = (size_t)(mrow + r) * NDIM + col;
      float v = sign * s[r];
      if (add) v += add[o];
      if (o32)  o32[o]  = v;
      if (o32b) o32b[o] = v;
      if (o16)  o16[o]  = (bf16_t)v;
      if (o16blk) o16blk[(size_t)(n0 >> 4) * 1024 + (mrow + r) * 16 + rl] = (bf16_t)v;
    }
  }
}

// --------------------------- mega nodes (512 thr) --------------------------
// A: W = U@invM, dual store Wrm+Wt (256 wgemm) || yMF = y@H^T (128 skinny)
__global__ __launch_bounds__(512, 4) void megaA(
    const bf16_t* __restrict__ U16, const bf16_t* __restrict__ iMt16,
    const bf16_t* __restrict__ y16, const bf16_t* __restrict__ H16,
    bf16_t* __restrict__ Wrm, bf16_t* __restrict__ Wt, bf16_t* __restrict__ yMF16) {
  __shared__ char smem[SMEM_BYTES];
  int b = blockIdx.x;
  if (b < 256) wgemm_role(U16, iMt16, Wrm, Wt, b, smem);
  else         skinny_role(y16, H16, (b - 256) * 16, smem, nullptr, 1.f,
                           nullptr, nullptr, yMF16, nullptr);
}

// B (light): c = yMF@invM (128) || x0 = yMF@Dinv (128 -> z0)
__global__ __launch_bounds__(512, 4) void megaB(
    const bf16_t* __restrict__ yMF16, const bf16_t* __restrict__ iMt16,
    const bf16_t* __restrict__ Dt16,
    float* __restrict__ c32, bf16_t* __restrict__ c16, bf16_t* __restrict__ z0) {
  __shared__ char smem[SMEM_BYTES];
  int b = blockIdx.x;
  if (b < 128) skinny_role(yMF16, iMt16, b * 16, smem, nullptr, 1.f, c32, nullptr, c16, nullptr);
  else         skinny_role(yMF16, Dt16, (b - 128) * 16, smem, nullptr, 1.f, nullptr, nullptr, z0, nullptr);
}

// C: W2 = NT(Wt,Wrm), dual store W2t+W2rm (256) || x1 (128 -> traj[1], z0+BSN)
//    || c2 (128)
__global__ __launch_bounds__(512, 4) void megaC(
    const bf16_t* __restrict__ Wt, const bf16_t* __restrict__ Wrm,
    const bf16_t* __restrict__ z0, const bf16_t* __restrict__ c16,
    const float* __restrict__ c32,
    bf16_t* __restrict__ W2t, bf16_t* __restrict__ W2rm,
    float* __restrict__ traj1, bf16_t* __restrict__ z0b,
    float* __restrict__ c2_32, bf16_t* __restrict__ c2_16) {
  __shared__ char smem[SMEM_BYTES];
  int b = blockIdx.x;
  if (b < 256)      wgemm_role(Wt, Wrm, W2t, W2rm, b, smem);
  else if (b < 384) skinny_role(z0, Wt, (b - 256) * 16, smem, c32, -1.f, traj1, nullptr, z0b, nullptr);
  else              skinny_role(c16, Wt, (b - 384) * 16, smem, c32, -1.f, c2_32, nullptr, c2_16, nullptr);
}

// D (light): x2 (128 -> traj[2], zA row + blk) || x3 (128 -> traj[3]) || c4 (128)
__global__ __launch_bounds__(512, 4) void megaD(
    const bf16_t* __restrict__ W2t, const bf16_t* __restrict__ z0,
    const bf16_t* __restrict__ c2_16, const float* __restrict__ c2_32,
    float* __restrict__ traj2, float* __restrict__ traj3,
    bf16_t* __restrict__ zA, bf16_t* __restrict__ zAblk, float* __restrict__ c4_32) {
  __shared__ char smem[SMEM_BYTES];
  int b = blockIdx.x;
  if (b < 128)      skinny_role(z0, W2t, b * 16, smem, c2_32, 1.f, traj2, nullptr, zA, zAblk);
  else if (b < 256) skinny_role(z0 + BSN, W2t, (b - 128) * 16, smem, c2_32, 1.f, traj3, nullptr,
                                zA + BSN, zAblk + BSN);
  else              skinny_role(c2_16, W2t, (b - 256) * 16, smem, c2_32, 1.f, c4_32, nullptr,
                                nullptr, nullptr);
}

// E: W4t = NT(W2t,W2rm) (256) || x4 (128 -> traj[4], blk chain2) || x5 (128 -> traj[5], blk chain3)
__global__ __launch_bounds__(512, 4) void megaE(
    const bf16_t* __restrict__ W2t, const bf16_t* __restrict__ W2rm,
    const bf16_t* __restrict__ zA_in, const float* __restrict__ c2_32,
    bf16_t* __restrict__ W4t, float* __restrict__ traj4, float* __restrict__ traj5,
    bf16_t* __restrict__ zAblk) {
  __shared__ char smem[SMEM_BYTES];
  int b = blockIdx.x;
  if (b < 256)      wgemm_role(W2t, W2rm, W4t, nullptr, b, smem);
  else if (b < 384) skinny_role(zA_in, W2t, (b - 256) * 16, smem, c2_32, 1.f, traj4, nullptr,
                                nullptr, zAblk + 2 * BSN);
  else              skinny_role(zA_in + BSN, W2t, (b - 384) * 16, smem, c2_32, 1.f, traj5, nullptr,
                                nullptr, zAblk + 3 * BSN);
}

// ---------------------------------------------------------------------------
// quad_fused v4 (unchanged from r4 -- matched prediction): all 5 quad steps
// in one fence-free launch; blocked write-through hand-off; per-(step,chain)
// relaxed counters.
// ---------------------------------------------------------------------------
__global__ __launch_bounds__(512, 4) void quad_fused(
    const bf16_t* __restrict__ zblk_in, const bf16_t* __restrict__ W4t,
    const float* __restrict__ c4_32, float* __restrict__ traj6,
    bf16_t* __restrict__ zsteps, float* __restrict__ sfin, int* __restrict__ bar) {
  __shared__ char smem[SMEM_BYTES];
  int b = blockIdx.x, ci = b & 3, p = b >> 2;
  int tid = threadIdx.x, lane = tid & 63, wave = tid >> 6;
  int rl = lane & 15, q = lane >> 4;
  int n0 = p * 16;
  // stage W4t panel once (fragment order), reused for all 5 steps
#pragma unroll
  for (int i = 0; i < 8; ++i) {
    const bf16_t* g = W4t + (size_t)(n0 + rl) * NDIM + (i * 8 + wave) * 32 + q * 8;
    gload16(g, smem + (size_t)(i * 512 + wave * 64) * 16);
  }
  __syncthreads();

  int ms = (wave & 3) * 16, kh = wave >> 2;
  const bf16x8* Bp = (const bf16x8*)smem + lane + kh * 2048;
  f32x4*  red  = (f32x4*)(smem + 65536);   // 4 KB
  bf16_t* pack = (bf16_t*)(smem + 69632);  // 2 KB panel pack
  const bf16_t* zcur = zblk_in + (size_t)ci * BSN;
  // per-thread blocked A offset in bf16x8 units
  int aoff = (ms + rl) * 2 + (q & 1) + (q >> 1) * 128 + kh * 8192;

#pragma unroll 1
  for (int g = 0; g < 5; ++g) {
    const bf16x8* Az = (const bf16x8*)zcur + aoff;
    f32x4 acc[8];
#pragma unroll
    for (int i = 0; i < 8; ++i) acc[i] = (f32x4){0.f, 0.f, 0.f, 0.f};
#pragma unroll
    for (int c = 0; c < 32; ++c)
      acc[c & 7] = __builtin_amdgcn_mfma_f32_16x16x32_bf16(Az[c * 256], Bp[c * 64], acc[c & 7], 0, 0, 0);
    f32x4 s = ((acc[0] + acc[1]) + (acc[2] + acc[3])) + ((acc[4] + acc[5]) + (acc[6] + acc[7]));

    if (wave >= 4) red[(wave & 3) * 64 + lane] = s;
    __syncthreads();
    bf16_t* zn = zsteps + (size_t)g * ZSTRIDE + (size_t)ci * BSN;  // fresh blocked buffer
    if (wave < 4) {
      s += red[wave * 64 + lane];
      int mrow = ms + q * 4, col = n0 + rl;
      float* tj = traj6 + (size_t)(4 * g + ci) * BSN;
#pragma unroll
      for (int r = 0; r < 4; ++r) {
        size_t o = (size_t)(mrow + r) * NDIM + col;
        float v = c4_32[o] + s[r];
        tj[o] = v;
        if (g == 4 && ci == 3) sfin[o] = v;
        if (g < 4) pack[(mrow + r) * 16 + rl] = (bf16_t)v;
      }
    }
    if (g < 4) {
      __syncthreads();                     // panel pack complete in LDS
      if (tid < 128) {                     // coalesced 16B/lane agent stores
        int row = tid >> 1, hf = tid & 1;
        const u64_t* src = (const u64_t*)pack + row * 4 + hf * 2;
        u64_t* dst = (u64_t*)(zn + (size_t)p * 1024) + row * 4 + hf * 2;
        __hip_atomic_store(dst,     src[0], __ATOMIC_RELAXED, __HIP_MEMORY_SCOPE_AGENT);
        __hip_atomic_store(dst + 1, src[1], __ATOMIC_RELAXED, __HIP_MEMORY_SCOPE_AGENT);
      }
      __syncthreads();   // s_waitcnt vmcnt(0): all sc1 stores at coherence point
      if (tid == 0) {
        int* ctr = &bar[(g * 4 + ci) * 32];  // 128B-separated per (step,chain)
        __hip_atomic_fetch_add(ctr, 1, __ATOMIC_RELAXED, __HIP_MEMORY_SCOPE_AGENT);
        while (__hip_atomic_load(ctr, __ATOMIC_RELAXED, __HIP_MEMORY_SCOPE_AGENT) < 128)
          __builtin_amdgcn_s_sleep(1);
        asm volatile("" ::: "memory");     // no acquire fence: fresh buffer, no stale lines
      }
      __syncthreads();
      zcur = zn;
    }
  }
}

// ---------------------------------------------------------------------------
// Host driver: memset + 7 kernel nodes.
// ---------------------------------------------------------------------------
extern "C" void kernel_launch(void* const* d_in, const int* in_sizes, int n_in,
                              void* d_out, int out_size, void* d_ws, size_t ws_size,
                              hipStream_t stream) {
  const float* y    = (const float*)d_in[2];
  const float* H    = (const float*)d_in[3];
  const float* Dinv = (const float*)d_in[4];
  const float* U    = (const float*)d_in[5];
  const float* invM = (const float*)d_in[6];

  float* out     = (float*)d_out;
  float* s_final = out;
  float* traj    = out + BSN;

  char* ws = (char*)d_ws;
  size_t off = 0;
  auto alloc = [&](size_t bytes) -> void* {
    void* p = ws + off;
    off += (bytes + 255) & ~(size_t)255;
    return p;
  };
  bf16_t* U16   = (bf16_t*)alloc((size_t)NDIM * NDIM * 2);  // -> W2rm after megaA
  bf16_t* Dt16  = (bf16_t*)alloc((size_t)NDIM * NDIM * 2);  // -> W4t after megaB
  bf16_t* iMt16 = (bf16_t*)alloc((size_t)NDIM * NDIM * 2);
  bf16_t* H16   = (bf16_t*)alloc((size_t)NDIM * NDIM * 2);  // -> W2t after megaA
  bf16_t* Wrm   = (bf16_t*)alloc((size_t)NDIM * NDIM * 2);
  bf16_t* Wt    = (bf16_t*)alloc((size_t)NDIM * NDIM * 2);
  bf16_t* y16   = (bf16_t*)alloc(BSN * 2);
  bf16_t* yMF16 = (bf16_t*)alloc(BSN * 2);
  bf16_t* c16   = (bf16_t*)alloc(BSN * 2);
  bf16_t* c2_16 = (bf16_t*)alloc(BSN * 2);
  float*  c32   = (float*)alloc(BSN * 4);
  float*  c2_32 = (float*)alloc(BSN * 4);
  float*  c4_32 = (float*)alloc(BSN * 4);
  bf16_t* z0    = (bf16_t*)alloc(2 * BSN * 2);          // x0, x1 (row-major)
  bf16_t* zA    = (bf16_t*)alloc(2 * BSN * 2);          // x2, x3 row-major (megaE A-operand)
  bf16_t* zAblk = (bf16_t*)alloc(4 * BSN * 2);          // x2..x5 blocked (quad input)
  bf16_t* zsteps= (bf16_t*)alloc(5 * ZSTRIDE * 2);      // 5 fresh per-step blocked slabs
  int*    bar   = (int*)alloc(4096);                    // 16 per-(step,chain) counters
  bf16_t* W2t   = H16;   // H16 dead after megaA
  bf16_t* W2rm  = U16;   // U16 dead after megaA
  bf16_t* W4t   = Dt16;  // Dt16 dead after megaB

  hipMemsetAsync(bar, 0, 4096, stream);

  prep<<<3072, 512, 0, stream>>>(H, U, Dinv, invM, y, H16, U16, Dt16, iMt16, y16, traj);
  megaA<<<384, 512, 0, stream>>>(U16, iMt16, y16, H16, Wrm, Wt, yMF16);
  megaB<<<256, 512, 0, stream>>>(yMF16, iMt16, Dt16, c32, c16, z0);
  megaC<<<512, 512, 0, stream>>>(Wt, Wrm, z0, c16, c32, W2t, W2rm,
                                 traj + BSN, z0 + BSN, c2_32, c2_16);
  megaD<<<384, 512, 0, stream>>>(W2t, z0, c2_16, c2_32, traj + 2 * BSN, traj + 3 * BSN,
                                 zA, zAblk, c4_32);
  megaE<<<512, 512, 0, stream>>>(W2t, W2rm, zA, c2_32, W4t, traj + 4 * BSN, traj + 5 * BSN,
                                 zAblk);

  // all 5 quad steps in one fence-free launch: fresh blocked slab per step,
  // writes traj[6..25] + s_final
  quad_fused<<<512, 512, 0, stream>>>(zAblk, W4t, c4_32, traj + 6 * BSN,
                                      zsteps, s_final, bar);
}